// Round 28
// baseline (490.778 us; speedup 1.0000x reference)
//
#include <hip/hip_runtime.h>
#include <hip/hip_bf16.h>

typedef __hip_bfloat16 bf16;
typedef __attribute__((ext_vector_type(8))) short bf16x8_t;
typedef __attribute__((ext_vector_type(4))) float f32x4_t;

#define N 2048
#define D 512
#define R 4
#define Q 32
#define NC 64
#define ALPHA 0.2f
#define LNEPS 1e-5f
#define NEGC -9e15f
#define PLS 36  // PV LDS row stride (shorts): 18 banks, gcd(18,32)=2 -> 16 rows hit 16 distinct banks

__device__ __forceinline__ float ldf(const float* p) { return *p; }
__device__ __forceinline__ float ldf(const bf16* p) { return __bfloat162float(*p); }
__device__ __forceinline__ void stf(float* p, float v) { *p = v; }
__device__ __forceinline__ void stf(bf16* p, float v) { *p = __float2bfloat16(v); }

__device__ __forceinline__ short f2b(float f) {  // RNE float->bf16 bits
    unsigned u = __builtin_bit_cast(unsigned, f);
    unsigned r = u + 0x7FFFu + ((u >> 16) & 1u);
    return (short)(r >> 16);
}
__device__ __forceinline__ float b2fs(short s) {
    unsigned u = ((unsigned)(unsigned short)s) << 16;
    return __builtin_bit_cast(float, u);
}
__device__ __forceinline__ unsigned pk2(float a, float b) {
    return (unsigned)(unsigned short)f2b(a) | (((unsigned)(unsigned short)f2b(b)) << 16);
}

__device__ __forceinline__ float waveReduceSum(float v) {
#pragma unroll
    for (int o = 32; o > 0; o >>= 1) v += __shfl_down(v, o, 64);
    return v;
}
__device__ __forceinline__ float waveReduceMax(float v) {
#pragma unroll
    for (int o = 32; o > 0; o >>= 1) v = fmaxf(v, __shfl_down(v, o, 64));
    return v;
}

// ---------------- prep: qemb, vvec, c0, qproj ----------------
__global__ __launch_bounds__(512) void k_prep(const float* __restrict__ qe1, const float* __restrict__ wq,
                                              const float* __restrict__ Wc, const float* __restrict__ bc,
                                              const float* __restrict__ Wqc, const float* __restrict__ bqc,
                                              float* __restrict__ qemb, float* __restrict__ vvec,
                                              float* __restrict__ qproj, float* __restrict__ c0) {
    __shared__ float logits[Q];
    __shared__ float sw[Q];
    __shared__ float meanq[D];
    __shared__ float qembs[D];
    __shared__ float red8[8];
    int tid = threadIdx.x;
    int wave = tid >> 6, lane = tid & 63;
    for (int q = wave; q < Q; q += 8) {
        float s = 0.f;
        for (int d = lane; d < D; d += 64) s += qe1[q * D + d] * wq[d];
        s = waveReduceSum(s);
        if (lane == 0) logits[q] = s;
    }
    __syncthreads();
    if (tid == 0) {
        float m = -3e38f;
        for (int q = 0; q < Q; q++) m = fmaxf(m, logits[q]);
        float ssum = 0.f;
        for (int q = 0; q < Q; q++) { float e = __expf(logits[q] - m); sw[q] = e; ssum += e; }
        float inv = 1.f / ssum;
        for (int q = 0; q < Q; q++) sw[q] *= inv;
    }
    __syncthreads();
    {
        float acc = 0.f, mq = 0.f;
#pragma unroll 4
        for (int q = 0; q < Q; q++) { float xv = qe1[q * D + tid]; acc += sw[q] * xv; mq += xv; }
        qembs[tid] = acc;
        meanq[tid] = mq * (1.f / Q);
        qemb[tid] = acc;
    }
    __syncthreads();
    {
        float v = 0.f, qp = 0.f;
        for (int i = 0; i < D; i++) {
            v = fmaf(qembs[i], Wc[i * D + tid], v);
            qp = fmaf(meanq[i], Wqc[i * D + tid], qp);
        }
        vvec[tid] = v;
        qproj[tid] = qp + bqc[tid];
    }
    float cc = qembs[tid] * bc[tid];
    cc = waveReduceSum(cc);
    if (lane == 0) red8[wave] = cc;
    __syncthreads();
    if (tid == 0) {
        float t = 0.f;
        for (int i = 0; i < 8; i++) t += red8[i];
        c0[0] = t;
    }
}

// ---------------- weight prep (per layer): W[r][k][d] f32 -> Wt[r][d][k] bf16 ----------------
__global__ __launch_bounds__(256) void k_prepw(const float* __restrict__ W, short* __restrict__ Wt) {
    int mi = blockIdx.z;
    int k0 = blockIdx.y * 32, d0 = blockIdx.x * 32;
    __shared__ float L[32][33];
    int tid = threadIdx.x;
    const float* Wm = W + (size_t)mi * D * D;
    {
        int kr = tid >> 3, dc = (tid & 7) * 4;
        float4 f = *(const float4*)&Wm[(size_t)(k0 + kr) * D + d0 + dc];
        L[kr][dc] = f.x; L[kr][dc + 1] = f.y; L[kr][dc + 2] = f.z; L[kr][dc + 3] = f.w;
    }
    __syncthreads();
    short* Wo = Wt + (size_t)mi * D * D;
    {
        int dr = tid >> 3, kc = (tid & 7) * 4;
        uint2 o;
        o.x = pk2(L[kc][dr], L[kc + 1][dr]);
        o.y = pk2(L[kc + 2][dr], L[kc + 3][dr]);
        *(uint2*)&Wo[(size_t)(d0 + dr) * D + k0 + kc] = o;
    }
}

// ---------------- zero f1/f2 (per layer, before fused GEMM accumulation) ----------------
__global__ __launch_bounds__(256) void k_zero12(float* __restrict__ f1, float* __restrict__ f2) {
    int i = blockIdx.x * 256 + threadIdx.x;  // R*N = 8192
    f1[i] = 0.f;
    f2[i] = 0.f;
}

// ---------------- gate -> bf16 xcur ----------------
__global__ __launch_bounds__(256) void k_gate(const float* __restrict__ x, const float* __restrict__ vvec,
                                              const float* __restrict__ qemb, const float* __restrict__ c0,
                                              bf16* __restrict__ xcur) {
    int n = blockIdx.x;
    int tid = threadIdx.x;
    __shared__ float red[4];
    __shared__ float ps;
    float x0 = x[n * D + tid], x1 = x[n * D + tid + 256];
    float v = x0 * vvec[tid] + x1 * vvec[tid + 256];
    v = waveReduceSum(v);
    if ((tid & 63) == 0) red[tid >> 6] = v;
    __syncthreads();
    if (tid == 0) {
        float dot = (red[0] + red[1]) + (red[2] + red[3]) + c0[0];
        ps = 1.f / (1.f + __expf(-dot));
    }
    __syncthreads();
    float p = ps;
    stf(&xcur[n * D + tid], p * x0 + (1.f - p) * qemb[tid]);
    stf(&xcur[n * D + tid + 256], p * x1 + (1.f - p) * qemb[tid + 256]);
}

// ---------------- MFMA GEMM + fused f1/f2: WhT[r][d][m] = (xin @ W[r])^T bf16 ----------------
__global__ __launch_bounds__(256) void k_gemm_mfma(const bf16* __restrict__ xin, const short* __restrict__ Wt,
                                                   short* __restrict__ WhT, const float* __restrict__ a1b,
                                                   const float* __restrict__ a2b, float* __restrict__ f1,
                                                   float* __restrict__ f2) {
    int r = blockIdx.z;
    int m0 = blockIdx.x * 64;
    int d0 = blockIdx.y * 64;
    int tid = threadIdx.x;
    int w = tid >> 6, l = tid & 63, g = l >> 4, rs = l & 15;
    int wn = w >> 1, wd = w & 1;
    __shared__ __align__(16) short Al[64 * 40];
    __shared__ __align__(16) short Bl[64 * 40];
    __shared__ __align__(16) short Tt[64 * 80];
    __shared__ float a1s[64], a2s[64];
    __shared__ float r1[4][64], r2[4][64];
    if (tid < 64) {
        a1s[tid] = a1b[r * D + d0 + tid];
        a2s[tid] = a2b[r * D + d0 + tid];
    }
    f32x4_t acc[2][2];
#pragma unroll
    for (int i = 0; i < 2; i++)
#pragma unroll
        for (int j = 0; j < 2; j++) acc[i][j] = (f32x4_t)(0.0f);

    const short* Wtr = Wt + (size_t)r * D * D;
    int sn = tid >> 2;
    int sk = (tid & 3) * 8;
    for (int k0 = 0; k0 < D; k0 += 32) {
        __syncthreads();
        {
            *(uint4*)&Al[sn * 40 + sk] = *(const uint4*)&xin[(size_t)(m0 + sn) * D + k0 + sk];
            *(uint4*)&Bl[sn * 40 + sk] = *(const uint4*)&Wtr[(size_t)(d0 + sn) * D + k0 + sk];
        }
        __syncthreads();
        union UA { bf16x8_t v; uint2 u[2]; };
        UA a[2], b;
#pragma unroll
        for (int nf = 0; nf < 2; nf++) {
            int arow = wn * 32 + nf * 16 + rs;
            a[nf].u[0] = *(const uint2*)&Al[arow * 40 + 4 * g];
            a[nf].u[1] = *(const uint2*)&Al[arow * 40 + 16 + 4 * g];
        }
#pragma unroll
        for (int df = 0; df < 2; df++) {
            int brow = wd * 32 + df * 16 + rs;
            b.u[0] = *(const uint2*)&Bl[brow * 40 + 4 * g];
            b.u[1] = *(const uint2*)&Bl[brow * 40 + 16 + 4 * g];
            acc[0][df] = __builtin_amdgcn_mfma_f32_16x16x32_bf16(a[0].v, b.v, acc[0][df], 0, 0, 0);
            acc[1][df] = __builtin_amdgcn_mfma_f32_16x16x32_bf16(a[1].v, b.v, acc[1][df], 0, 0, 0);
        }
    }
    __syncthreads();
    // D layout (m89): col(lane&15)->d, row(4*(lane>>4)+reg)->m. Stage Tt[d][m], coalesced store.
#pragma unroll
    for (int nf = 0; nf < 2; nf++)
#pragma unroll
        for (int df = 0; df < 2; df++) {
            int nl = wn * 32 + nf * 16 + 4 * g;
            int dl = wd * 32 + df * 16 + rs;
            uint2 o;
            o.x = pk2(acc[nf][df][0], acc[nf][df][1]);
            o.y = pk2(acc[nf][df][2], acc[nf][df][3]);
            *(uint2*)&Tt[dl * 80 + nl] = o;
        }
    __syncthreads();
    {
        int dl = tid >> 2;
        int nc = (tid & 3) * 16;
        uint4 v0 = *(const uint4*)&Tt[dl * 80 + nc];
        uint4 v1 = *(const uint4*)&Tt[dl * 80 + nc + 8];
        short* op = WhT + ((size_t)r * D + d0 + dl) * N + m0 + nc;
        *(uint4*)op = v0;
        *(uint4*)(op + 8) = v1;
    }
    // fused f1/f2 partials from Tt (same bf16 values k_f12t would have read)
    {
        int m = tid & 63, dg = tid >> 6;
        float s1 = 0.f, s2 = 0.f;
#pragma unroll
        for (int d = 0; d < 16; d++) {
            int dd = dg + d * 4;
            float wv = b2fs(Tt[dd * 80 + m]);
            s1 = fmaf(wv, a1s[dd], s1);
            s2 = fmaf(wv, a2s[dd], s2);
        }
        r1[dg][m] = s1;
        r2[dg][m] = s2;
    }
    __syncthreads();
    if (tid < 64) {
        float v1 = (r1[0][tid] + r1[1][tid]) + (r1[2][tid] + r1[3][tid]);
        float v2 = (r2[0][tid] + r2[1][tid]) + (r2[2][tid] + r2[3][tid]);
        atomicAdd(&f1[r * N + m0 + tid], v1);
        atomicAdd(&f2[r * N + m0 + tid], v2);
    }
}

// ---------------- fused PV: n-SPLIT (16 rows/block, grid 512 -> real 2 blocks/CU) ----------------
// r27 base + one change: 32 -> 16 n-rows per block, grid (N/16, R) = 512 blocks. Producers work
// disjoint rows (NO duplicated VALU, unlike r19's d-split); stagers duplicate WhT staging (L2-hit).
// 16 rows x 16 threads x 2 m-cols per producer; MFMA: single A-fragment, acc[4]; LDS ~76 KB.
__global__ __launch_bounds__(512, 2) void k_pv_nm(const int* __restrict__ adj, const float* __restrict__ f1,
                                                  const float* __restrict__ f2, const short* __restrict__ WhT,
                                                  bf16* __restrict__ xr) {
    int r = blockIdx.y;
    int n0 = blockIdx.x * 16;
    int tid = threadIdx.x;
    int w = tid >> 6, l = tid & 63, g = l >> 4, rs = l & 15;
    __shared__ __align__(16) short Pl[2][16 * PLS];
    __shared__ __align__(16) short Whl[2][512 * PLS];
    __shared__ float sl[16], f1s[16];
    if (tid < 16) f1s[tid] = f1[r * N + n0 + tid];
    __syncthreads();
    f32x4_t acc[4];
#pragma unroll
    for (int i = 0; i < 4; i++) acc[i] = (f32x4_t)(0.0f);

    // producer: row pn (0..15), m-pair pm2 (0,2,..,30)
    int pn = tid >> 4, pm2 = (tid & 15) * 2;
    const float* f2r = f2 + r * N;
    const int* arowb = adj + ((size_t)r * N + n0 + (pn & 15)) * N + pm2;
    int2 avA, avB;
    float2 fvA, fvB;
    float f1v = 0.f;
    float myl = 0.f;
    int j = tid - 256;
    uint4 wreg[8];
    if (tid < 256) {
        f1v = f1s[pn];
        avA = *(const int2*)(arowb);
        fvA = *(const float2*)&f2r[pm2];
        avB = *(const int2*)(arowb + 32);
        fvB = *(const float2*)&f2r[32 + pm2];
    } else {
        // prologue: load tile 0 into wreg
#pragma unroll
        for (int i = 0; i < 8; i++) {
            int v = j + i * 256;
            int dd = v >> 2, mc = (v & 3) * 8;
            wreg[i] = *(const uint4*)&WhT[((size_t)r * D + dd) * N + mc];
        }
    }

    const int NT = N / 32;  // 64 (even)

    // PRODUCE(tile tt -> buffer cc): producer computes P(tt) (2 cols) w/ depth-2 adj prefetch;
    // stager writes wreg (tile tt) to Whl[cc], then loads tile tt+1 into wreg.
#define PRODUCE(tt, cc, AV, FV)                                                                      \
    if (tid < 256) {                                                                                 \
        float t0 = f1v + FV.x; t0 = t0 >= 0.f ? t0 : ALPHA * t0;                                     \
        float t1 = f1v + FV.y; t1 = t1 >= 0.f ? t1 : ALPHA * t1;                                     \
        float e0 = (AV.x > 0) ? __expf(fminf(t0, 60.f)) : 0.f;                                       \
        float e1 = (AV.y > 0) ? __expf(fminf(t1, 60.f)) : 0.f;                                       \
        myl += e0 + e1;                                                                              \
        *(unsigned*)&Pl[cc][pn * PLS + pm2] = pk2(e0, e1);                                           \
        if ((tt) + 2 < NT) {                                                                         \
            AV = *(const int2*)(arowb + ((tt) + 2) * 32);                                            \
            FV = *(const float2*)&f2r[((tt) + 2) * 32 + pm2];                                        \
        }                                                                                            \
    } else {                                                                                         \
        _Pragma("unroll") for (int i = 0; i < 8; i++) {                                              \
            int v = j + i * 256;                                                                     \
            int dd = v >> 2, mc = (v & 3) * 8;                                                       \
            uint2 lo; lo.x = wreg[i].x; lo.y = wreg[i].y;                                            \
            uint2 hi; hi.x = wreg[i].z; hi.y = wreg[i].w;                                            \
            *(uint2*)&Whl[cc][dd * PLS + mc] = lo;                                                   \
            *(uint2*)&Whl[cc][dd * PLS + mc + 4] = hi;                                               \
        }                                                                                            \
        if ((tt) + 1 < NT) {                                                                         \
            _Pragma("unroll") for (int i = 0; i < 8; i++) {                                          \
                int v = j + i * 256;                                                                 \
                int dd = v >> 2, mc = (v & 3) * 8;                                                   \
                wreg[i] = *(const uint4*)&WhT[((size_t)r * D + dd) * N + ((tt) + 1) * 32 + mc];      \
            }                                                                                        \
        }                                                                                            \
    }

#define MFMASTEP(cc)                                                                                 \
    {                                                                                                \
        union UA { bf16x8_t v; uint2 u[2]; };                                                        \
        UA a, bb;                                                                                    \
        a.u[0] = *(const uint2*)&Pl[cc][rs * PLS + 4 * g];                                           \
        a.u[1] = *(const uint2*)&Pl[cc][rs * PLS + 16 + 4 * g];                                      \
        _Pragma("unroll") for (int df = 0; df < 4; df++) {                                           \
            int brow = w * 64 + df * 16 + rs;                                                        \
            bb.u[0] = *(const uint2*)&Whl[cc][brow * PLS + 4 * g];                                   \
            bb.u[1] = *(const uint2*)&Whl[cc][brow * PLS + 16 + 4 * g];                              \
            acc[df] = __builtin_amdgcn_mfma_f32_16x16x32_bf16(a.v, bb.v, acc[df], 0, 0, 0);          \
        }                                                                                            \
    }

    PRODUCE(0, 0, avA, fvA);
    __syncthreads();
    for (int t = 0; t < NT; t += 2) {
        if (t + 1 < NT) { PRODUCE(t + 1, 1, avB, fvB); }
        MFMASTEP(0);
        __syncthreads();
        if (t + 2 < NT) { PRODUCE(t + 2, 0, avA, fvA); }
        MFMASTEP(1);
        __syncthreads();
    }
#undef PRODUCE
#undef MFMASTEP
    // final l: reduce myl over the 16 producer threads of each row, publish, normalize, ELU, store.
    if (tid < 256) {
        float v = myl;
#pragma unroll
        for (int msk = 1; msk < 16; msk <<= 1) v += __shfl_xor(v, msk, 16);
        if ((tid & 15) == 0) sl[pn] = v;
    }
    __syncthreads();
    float inv[4];
#pragma unroll
    for (int reg = 0; reg < 4; reg++) inv[reg] = 1.f / sl[4 * g + reg];
#pragma unroll
    for (int df = 0; df < 4; df++)
#pragma unroll
        for (int reg = 0; reg < 4; reg++) {
            int n = n0 + 4 * g + reg;
            int d = w * 64 + df * 16 + rs;
            float v = acc[df][reg] * inv[reg];
            v = v > 0.f ? v : (__expf(v) - 1.f);
            stf(&xr[((size_t)r * N + n) * D + d], v);
        }
}

// ---------------- LayerNorm per (r,n) row then max over r (bf16->bf16) ----------------
__global__ __launch_bounds__(256) void k_lnmax(const bf16* __restrict__ xr, const float* __restrict__ g,
                                               const float* __restrict__ b, bf16* __restrict__ xout) {
    int n = blockIdx.x;
    int tid = threadIdx.x;
    int wave = tid >> 6, lane = tid & 63;
    __shared__ float redA[4], redB[4];
    float g0 = g[tid], g1 = g[tid + 256];
    float bb0 = b[tid], bb1 = b[tid + 256];
    float mx0 = -3e38f, mx1 = -3e38f;
    for (int r = 0; r < R; r++) {
        const bf16* row = xr + ((size_t)(r * N + n)) * D;
        float v0 = ldf(&row[tid]), v1 = ldf(&row[tid + 256]);
        float s = v0 + v1;
        float ss = fmaf(v0, v0, v1 * v1);
        s = waveReduceSum(s);
        ss = waveReduceSum(ss);
        if (lane == 0) { redA[wave] = s; redB[wave] = ss; }
        __syncthreads();
        float mu = ((redA[0] + redA[1]) + (redA[2] + redA[3])) * (1.f / D);
        float ex2 = ((redB[0] + redB[1]) + (redB[2] + redB[3])) * (1.f / D);
        float inv = 1.f / sqrtf(ex2 - mu * mu + LNEPS);
        mx0 = fmaxf(mx0, (v0 - mu) * inv * g0 + bb0);
        mx1 = fmaxf(mx1, (v1 - mu) * inv * g1 + bb1);
        __syncthreads();
    }
    stf(&xout[n * D + tid], mx0);
    stf(&xout[n * D + tid + 256], mx1);
}

// ---------------- final decoder round: max over r, f32 out ----------------
__global__ __launch_bounds__(256) void k_maxout(const bf16* __restrict__ xr, float* __restrict__ out) {
    size_t idx = (size_t)blockIdx.x * 256 + threadIdx.x;
    float m = ldf(&xr[idx]);
    m = fmaxf(m, ldf(&xr[(size_t)N * D + idx]));
    m = fmaxf(m, ldf(&xr[2 * (size_t)N * D + idx]));
    m = fmaxf(m, ldf(&xr[3 * (size_t)N * D + idx]));
    out[idx] = m;
}

// ---------------- choices head, phase 1: per-candidate dots ----------------
__global__ __launch_bounds__(256) void k_cscore(const bf16* __restrict__ xe, const int* __restrict__ cidx,
                                                const float* __restrict__ qproj, const float* __restrict__ Wout,
                                                float* __restrict__ scw, float* __restrict__ dvw) {
    int wv = threadIdx.x >> 6, lane = threadIdx.x & 63;
    int p = blockIdx.x * 4 + wv;  // 0..319 = k*64+c
    const bf16* row = xe + (size_t)cidx[p] * D;
    float s1 = 0.f, s2 = 0.f;
#pragma unroll
    for (int i = 0; i < 8; i++) {
        int d = lane + i * 64;
        float v = ldf(&row[d]);
        s1 = fmaf(v, qproj[d], s1);
        s2 = fmaf(v, Wout[d], s2);
    }
    s1 = waveReduceSum(s1);
    s2 = waveReduceSum(s2);
    if (lane == 0) { scw[p] = s1; dvw[p] = s2; }
}

// ---------------- choices head, phase 2: softmax + logits + log_softmax ----------------
__global__ __launch_bounds__(64) void k_cfinal(const float* __restrict__ scw, const float* __restrict__ dvw,
                                               const float* __restrict__ bout, float* __restrict__ out) {
    int lane = threadIdx.x;
    __shared__ float lg[5];
    for (int k = 0; k < 5; k++) {
        float v = scw[k * NC + lane];
        float m = waveReduceMax(v);
        m = __shfl(m, 0, 64);
        float e = __expf(v - m);
        float s = waveReduceSum(e);
        s = __shfl(s, 0, 64);
        float t = (e / s) * dvw[k * NC + lane];
        t = waveReduceSum(t);
        if (lane == 0) lg[k] = t + bout[0];
    }
    __syncthreads();
    if (lane == 0) {
        float m = -3e38f;
        for (int k = 0; k < 5; k++) m = fmaxf(m, lg[k]);
        float s = 0.f;
        for (int k = 0; k < 5; k++) s += __expf(lg[k] - m);
        float lse = logf(s) + m;
        for (int k = 0; k < 5; k++) out[k] = lg[k] - lse;
    }
}

extern "C" void kernel_launch(void* const* d_in, const int* in_sizes, int n_in,
                              void* d_out, int out_size, void* d_ws, size_t ws_size,
                              hipStream_t stream) {
    bool skipQ = false;
    if (n_in > 4 && in_sizes[4] != 5 * NC && in_sizes[3] == 5 * NC) skipQ = true;
    auto IN = [&](int i) -> const void* {
        int j = (skipQ && i >= 4) ? i - 1 : i;
        return d_in[j];
    };
    const float* x = (const float*)IN(0);
    const int* adj = (const int*)IN(1);
    const float* qe1 = (const float*)IN(2);
    const int* cidx = (const int*)IN(4);
    const float* Wc = (const float*)IN(5);
    const float* bc = (const float*)IN(6);
    const float* wq = (const float*)IN(7);
    const float* encW = (const float*)IN(8);
    const float* enca1 = (const float*)IN(9);
    const float* enca2 = (const float*)IN(10);
    const float* decW = (const float*)IN(11);
    const float* deca1 = (const float*)IN(12);
    const float* deca2 = (const float*)IN(13);
    const float* lng = (const float*)IN(14);
    const float* lnb = (const float*)IN(15);
    const float* Wqc = (const float*)IN(16);
    const float* bqc = (const float*)IN(17);
    const float* Wout = (const float*)IN(18);
    const float* bout = (const float*)IN(19);
    float* out = (float*)d_out;  // f32 output (proven round 6)

    // Workspace: 21,110,784 B total — round-7-proven footprint.
    char* w8 = (char*)d_ws;
    float* qemb = (float*)(w8 + 0);
    float* vvec = (float*)(w8 + 2048);
    float* qproj = (float*)(w8 + 4096);
    float* c0 = (float*)(w8 + 6144);
    float* f1 = (float*)(w8 + 8192);
    float* f2 = (float*)(w8 + 8192 + 32768);
    float* scw = (float*)(w8 + 8192 + 65536);
    float* dvw = (float*)(w8 + 8192 + 98304);
    const size_t ND = (size_t)N * D;
    bf16* xcur = (bf16*)(w8 + 139264);                       // 2 MB
    bf16* xd = (bf16*)(w8 + 139264 + ND * 2);                // 2 MB
    short* WhT = (short*)(w8 + 139264 + ND * 4);             // 8 MB
    bf16* xr = (bf16*)(w8 + 139264 + ND * 4 + R * ND * 2);   // 8 MB
    short* Wt = (short*)xr;  // per-layer bf16 weights (2 MB) alias xr; lifetimes disjoint

    k_prep<<<1, 512, 0, stream>>>(qe1, wq, Wc, bc, Wqc, bqc, qemb, vvec, qproj, c0);
    k_gate<<<N, 256, 0, stream>>>(x, vvec, qemb, c0, xcur);

    for (int L = 0; L < 4; L++) {
        const float* Wb = (L < 2) ? encW + (size_t)L * R * D * D : decW + (size_t)(L - 2) * R * D * D;
        const float* a1 = (L < 2) ? enca1 + L * R * D : deca1 + (L - 2) * R * D;
        const float* a2 = (L < 2) ? enca2 + L * R * D : deca2 + (L - 2) * R * D;
        const bf16* xin = (L == 3) ? xd : xcur;
        k_prepw<<<dim3(16, 16, R), 256, 0, stream>>>(Wb, Wt);
        k_zero12<<<R * N / 256, 256, 0, stream>>>(f1, f2);
        k_gemm_mfma<<<dim3(N / 64, D / 64, R), 256, 0, stream>>>(xin, Wt, WhT, a1, a2, f1, f2);
        k_pv_nm<<<dim3(N / 16, R), 512, 0, stream>>>(adj, f1, f2, WhT, xr);
        if (L < 3)
            k_lnmax<<<N, 256, 0, stream>>>(xr, lng, lnb, (L < 2) ? xcur : xd);
        else
            k_maxout<<<N * D / 256, 256, 0, stream>>>(xr, out + 5);
    }
    k_cscore<<<80, 256, 0, stream>>>(xcur, cidx, qproj, Wout, scw, dvw);
    k_cfinal<<<1, 64, 0, stream>>>(scw, dvw, bout, out);
}

// Round 29
// 384.629 us; speedup vs baseline: 1.2760x; 1.2760x over previous
//
#include <hip/hip_runtime.h>
#include <hip/hip_bf16.h>

typedef __hip_bfloat16 bf16;
typedef __attribute__((ext_vector_type(8))) short bf16x8_t;
typedef __attribute__((ext_vector_type(4))) float f32x4_t;

#define N 2048
#define D 512
#define R 4
#define Q 32
#define NC 64
#define ALPHA 0.2f
#define LNEPS 1e-5f
#define NEGC -9e15f
#define PLS 44  // PV LDS row stride (shorts): 22 banks, gcd(22,32)=2 -> 16 rows hit 16 distinct banks

__device__ __forceinline__ float ldf(const float* p) { return *p; }
__device__ __forceinline__ float ldf(const bf16* p) { return __bfloat162float(*p); }
__device__ __forceinline__ void stf(float* p, float v) { *p = v; }
__device__ __forceinline__ void stf(bf16* p, float v) { *p = __float2bfloat16(v); }

__device__ __forceinline__ short f2b(float f) {  // RNE float->bf16 bits
    unsigned u = __builtin_bit_cast(unsigned, f);
    unsigned r = u + 0x7FFFu + ((u >> 16) & 1u);
    return (short)(r >> 16);
}
__device__ __forceinline__ float b2fs(short s) {
    unsigned u = ((unsigned)(unsigned short)s) << 16;
    return __builtin_bit_cast(float, u);
}
__device__ __forceinline__ unsigned pk2(float a, float b) {
    return (unsigned)(unsigned short)f2b(a) | (((unsigned)(unsigned short)f2b(b)) << 16);
}

__device__ __forceinline__ float waveReduceSum(float v) {
#pragma unroll
    for (int o = 32; o > 0; o >>= 1) v += __shfl_down(v, o, 64);
    return v;
}
__device__ __forceinline__ float waveReduceMax(float v) {
#pragma unroll
    for (int o = 32; o > 0; o >>= 1) v = fmaxf(v, __shfl_down(v, o, 64));
    return v;
}

// ---------------- prep: qemb, vvec, c0, qproj ----------------
__global__ __launch_bounds__(512) void k_prep(const float* __restrict__ qe1, const float* __restrict__ wq,
                                              const float* __restrict__ Wc, const float* __restrict__ bc,
                                              const float* __restrict__ Wqc, const float* __restrict__ bqc,
                                              float* __restrict__ qemb, float* __restrict__ vvec,
                                              float* __restrict__ qproj, float* __restrict__ c0) {
    __shared__ float logits[Q];
    __shared__ float sw[Q];
    __shared__ float meanq[D];
    __shared__ float qembs[D];
    __shared__ float red8[8];
    int tid = threadIdx.x;
    int wave = tid >> 6, lane = tid & 63;
    for (int q = wave; q < Q; q += 8) {
        float s = 0.f;
        for (int d = lane; d < D; d += 64) s += qe1[q * D + d] * wq[d];
        s = waveReduceSum(s);
        if (lane == 0) logits[q] = s;
    }
    __syncthreads();
    if (tid == 0) {
        float m = -3e38f;
        for (int q = 0; q < Q; q++) m = fmaxf(m, logits[q]);
        float ssum = 0.f;
        for (int q = 0; q < Q; q++) { float e = __expf(logits[q] - m); sw[q] = e; ssum += e; }
        float inv = 1.f / ssum;
        for (int q = 0; q < Q; q++) sw[q] *= inv;
    }
    __syncthreads();
    {
        float acc = 0.f, mq = 0.f;
#pragma unroll 4
        for (int q = 0; q < Q; q++) { float xv = qe1[q * D + tid]; acc += sw[q] * xv; mq += xv; }
        qembs[tid] = acc;
        meanq[tid] = mq * (1.f / Q);
        qemb[tid] = acc;
    }
    __syncthreads();
    {
        float v = 0.f, qp = 0.f;
        for (int i = 0; i < D; i++) {
            v = fmaf(qembs[i], Wc[i * D + tid], v);
            qp = fmaf(meanq[i], Wqc[i * D + tid], qp);
        }
        vvec[tid] = v;
        qproj[tid] = qp + bqc[tid];
    }
    float cc = qembs[tid] * bc[tid];
    cc = waveReduceSum(cc);
    if (lane == 0) red8[wave] = cc;
    __syncthreads();
    if (tid == 0) {
        float t = 0.f;
        for (int i = 0; i < 8; i++) t += red8[i];
        c0[0] = t;
    }
}

// ---------------- weight prep (per layer): W[r][k][d] f32 -> Wt[r][d][k] bf16 ----------------
__global__ __launch_bounds__(256) void k_prepw(const float* __restrict__ W, short* __restrict__ Wt) {
    int mi = blockIdx.z;
    int k0 = blockIdx.y * 32, d0 = blockIdx.x * 32;
    __shared__ float L[32][33];
    int tid = threadIdx.x;
    const float* Wm = W + (size_t)mi * D * D;
    {
        int kr = tid >> 3, dc = (tid & 7) * 4;
        float4 f = *(const float4*)&Wm[(size_t)(k0 + kr) * D + d0 + dc];
        L[kr][dc] = f.x; L[kr][dc + 1] = f.y; L[kr][dc + 2] = f.z; L[kr][dc + 3] = f.w;
    }
    __syncthreads();
    short* Wo = Wt + (size_t)mi * D * D;
    {
        int dr = tid >> 3, kc = (tid & 7) * 4;
        uint2 o;
        o.x = pk2(L[kc][dr], L[kc + 1][dr]);
        o.y = pk2(L[kc + 2][dr], L[kc + 3][dr]);
        *(uint2*)&Wo[(size_t)(d0 + dr) * D + k0 + kc] = o;
    }
}

// ---------------- zero f1/f2 (per layer, before fused GEMM accumulation) ----------------
__global__ __launch_bounds__(256) void k_zero12(float* __restrict__ f1, float* __restrict__ f2) {
    int i = blockIdx.x * 256 + threadIdx.x;  // R*N = 8192
    f1[i] = 0.f;
    f2[i] = 0.f;
}

// ---------------- gate -> bf16 xcur ----------------
__global__ __launch_bounds__(256) void k_gate(const float* __restrict__ x, const float* __restrict__ vvec,
                                              const float* __restrict__ qemb, const float* __restrict__ c0,
                                              bf16* __restrict__ xcur) {
    int n = blockIdx.x;
    int tid = threadIdx.x;
    __shared__ float red[4];
    __shared__ float ps;
    float x0 = x[n * D + tid], x1 = x[n * D + tid + 256];
    float v = x0 * vvec[tid] + x1 * vvec[tid + 256];
    v = waveReduceSum(v);
    if ((tid & 63) == 0) red[tid >> 6] = v;
    __syncthreads();
    if (tid == 0) {
        float dot = (red[0] + red[1]) + (red[2] + red[3]) + c0[0];
        ps = 1.f / (1.f + __expf(-dot));
    }
    __syncthreads();
    float p = ps;
    stf(&xcur[n * D + tid], p * x0 + (1.f - p) * qemb[tid]);
    stf(&xcur[n * D + tid + 256], p * x1 + (1.f - p) * qemb[tid + 256]);
}

// ---------------- MFMA GEMM + fused f1/f2: WhT[r][d][m] = (xin @ W[r])^T bf16 ----------------
__global__ __launch_bounds__(256) void k_gemm_mfma(const bf16* __restrict__ xin, const short* __restrict__ Wt,
                                                   short* __restrict__ WhT, const float* __restrict__ a1b,
                                                   const float* __restrict__ a2b, float* __restrict__ f1,
                                                   float* __restrict__ f2) {
    int r = blockIdx.z;
    int m0 = blockIdx.x * 64;
    int d0 = blockIdx.y * 64;
    int tid = threadIdx.x;
    int w = tid >> 6, l = tid & 63, g = l >> 4, rs = l & 15;
    int wn = w >> 1, wd = w & 1;
    __shared__ __align__(16) short Al[64 * 40];
    __shared__ __align__(16) short Bl[64 * 40];
    __shared__ __align__(16) short Tt[64 * 80];
    __shared__ float a1s[64], a2s[64];
    __shared__ float r1[4][64], r2[4][64];
    if (tid < 64) {
        a1s[tid] = a1b[r * D + d0 + tid];
        a2s[tid] = a2b[r * D + d0 + tid];
    }
    f32x4_t acc[2][2];
#pragma unroll
    for (int i = 0; i < 2; i++)
#pragma unroll
        for (int j = 0; j < 2; j++) acc[i][j] = (f32x4_t)(0.0f);

    const short* Wtr = Wt + (size_t)r * D * D;
    int sn = tid >> 2;
    int sk = (tid & 3) * 8;
    for (int k0 = 0; k0 < D; k0 += 32) {
        __syncthreads();
        {
            *(uint4*)&Al[sn * 40 + sk] = *(const uint4*)&xin[(size_t)(m0 + sn) * D + k0 + sk];
            *(uint4*)&Bl[sn * 40 + sk] = *(const uint4*)&Wtr[(size_t)(d0 + sn) * D + k0 + sk];
        }
        __syncthreads();
        union UA { bf16x8_t v; uint2 u[2]; };
        UA a[2], b;
#pragma unroll
        for (int nf = 0; nf < 2; nf++) {
            int arow = wn * 32 + nf * 16 + rs;
            a[nf].u[0] = *(const uint2*)&Al[arow * 40 + 4 * g];
            a[nf].u[1] = *(const uint2*)&Al[arow * 40 + 16 + 4 * g];
        }
#pragma unroll
        for (int df = 0; df < 2; df++) {
            int brow = wd * 32 + df * 16 + rs;
            b.u[0] = *(const uint2*)&Bl[brow * 40 + 4 * g];
            b.u[1] = *(const uint2*)&Bl[brow * 40 + 16 + 4 * g];
            acc[0][df] = __builtin_amdgcn_mfma_f32_16x16x32_bf16(a[0].v, b.v, acc[0][df], 0, 0, 0);
            acc[1][df] = __builtin_amdgcn_mfma_f32_16x16x32_bf16(a[1].v, b.v, acc[1][df], 0, 0, 0);
        }
    }
    __syncthreads();
    // D layout (m89): col(lane&15)->d, row(4*(lane>>4)+reg)->m. Stage Tt[d][m], coalesced store.
#pragma unroll
    for (int nf = 0; nf < 2; nf++)
#pragma unroll
        for (int df = 0; df < 2; df++) {
            int nl = wn * 32 + nf * 16 + 4 * g;
            int dl = wd * 32 + df * 16 + rs;
            uint2 o;
            o.x = pk2(acc[nf][df][0], acc[nf][df][1]);
            o.y = pk2(acc[nf][df][2], acc[nf][df][3]);
            *(uint2*)&Tt[dl * 80 + nl] = o;
        }
    __syncthreads();
    {
        int dl = tid >> 2;
        int nc = (tid & 3) * 16;
        uint4 v0 = *(const uint4*)&Tt[dl * 80 + nc];
        uint4 v1 = *(const uint4*)&Tt[dl * 80 + nc + 8];
        short* op = WhT + ((size_t)r * D + d0 + dl) * N + m0 + nc;
        *(uint4*)op = v0;
        *(uint4*)(op + 8) = v1;
    }
    // fused f1/f2 partials from Tt (same bf16 values k_f12t would have read)
    {
        int m = tid & 63, dg = tid >> 6;
        float s1 = 0.f, s2 = 0.f;
#pragma unroll
        for (int d = 0; d < 16; d++) {
            int dd = dg + d * 4;
            float wv = b2fs(Tt[dd * 80 + m]);
            s1 = fmaf(wv, a1s[dd], s1);
            s2 = fmaf(wv, a2s[dd], s2);
        }
        r1[dg][m] = s1;
        r2[dg][m] = s2;
    }
    __syncthreads();
    if (tid < 64) {
        float v1 = (r1[0][tid] + r1[1][tid]) + (r1[2][tid] + r1[3][tid]);
        float v2 = (r2[0][tid] + r2[1][tid]) + (r2[2][tid] + r2[3][tid]);
        atomicAdd(&f1[r * N + m0 + tid], v1);
        atomicAdd(&f2[r * N + m0 + tid], v2);
    }
}

// ---------------- fused PV: r26 base + T5 s_setprio around the MFMA cluster ----------------
// Role-split schedule (4 producer waves / 4 stager waves) is T5's paying regime: raising a
// wave's priority while it runs its MFMA cluster lets the CU scheduler favor it over waves
// still issuing loads/LDS writes, tightening the inter-barrier critical path.
__global__ __launch_bounds__(512, 2) void k_pv_nm(const int* __restrict__ adj, const float* __restrict__ f1,
                                                  const float* __restrict__ f2, const short* __restrict__ WhT,
                                                  bf16* __restrict__ xr) {
    int r = blockIdx.y;
    int n0 = blockIdx.x * 32;
    int tid = threadIdx.x;
    int w = tid >> 6, l = tid & 63, g = l >> 4, rs = l & 15;
    __shared__ __align__(16) short Pl[2][32 * PLS];
    __shared__ __align__(16) short Whl[2][512 * PLS];
    __shared__ float sl[32], f1s[32];
    if (tid < 32) f1s[tid] = f1[r * N + n0 + tid];
    __syncthreads();
    f32x4_t acc[2][4];
#pragma unroll
    for (int i = 0; i < 2; i++)
#pragma unroll
        for (int j = 0; j < 4; j++) acc[i][j] = (f32x4_t)(0.0f);

    int pn = tid >> 3, pm4 = (tid & 7) * 4;
    const float* f2r = f2 + r * N;
    const int* arowb = adj + ((size_t)r * N + n0 + (pn & 31)) * N + pm4;
    int4 avA, avB;
    float4 fvA, fvB;
    float f1v = 0.f;
    float myl = 0.f;
    int j = tid - 256;
    uint4 wreg[8];
    if (tid < 256) {
        f1v = f1s[pn];
        avA = *(const int4*)(arowb);
        fvA = *(const float4*)&f2r[pm4];
        avB = *(const int4*)(arowb + 32);
        fvB = *(const float4*)&f2r[32 + pm4];
    } else {
        // prologue: load tile 0 into wreg
#pragma unroll
        for (int i = 0; i < 8; i++) {
            int v = j + i * 256;
            int dd = v >> 2, mc = (v & 3) * 8;
            wreg[i] = *(const uint4*)&WhT[((size_t)r * D + dd) * N + mc];
        }
    }

    const int NT = N / 32;  // 64 (even)

    // PRODUCE(tile tt -> buffer cc): producer computes P(tt) w/ depth-2 adj prefetch;
    // stager writes wreg (tile tt) to Whl[cc], then loads tile tt+1 into wreg.
#define PRODUCE(tt, cc, AV, FV)                                                                      \
    if (tid < 256) {                                                                                 \
        float t0 = f1v + FV.x; t0 = t0 >= 0.f ? t0 : ALPHA * t0;                                     \
        float t1 = f1v + FV.y; t1 = t1 >= 0.f ? t1 : ALPHA * t1;                                     \
        float t2 = f1v + FV.z; t2 = t2 >= 0.f ? t2 : ALPHA * t2;                                     \
        float t3 = f1v + FV.w; t3 = t3 >= 0.f ? t3 : ALPHA * t3;                                     \
        float e0 = (AV.x > 0) ? __expf(fminf(t0, 60.f)) : 0.f;                                       \
        float e1 = (AV.y > 0) ? __expf(fminf(t1, 60.f)) : 0.f;                                       \
        float e2 = (AV.z > 0) ? __expf(fminf(t2, 60.f)) : 0.f;                                       \
        float e3 = (AV.w > 0) ? __expf(fminf(t3, 60.f)) : 0.f;                                       \
        myl += (e0 + e1) + (e2 + e3);                                                                \
        uint2 pw;                                                                                    \
        pw.x = pk2(e0, e1);                                                                          \
        pw.y = pk2(e2, e3);                                                                          \
        *(uint2*)&Pl[cc][pn * PLS + pm4] = pw;                                                       \
        if ((tt) + 2 < NT) {                                                                         \
            AV = *(const int4*)(arowb + ((tt) + 2) * 32);                                            \
            FV = *(const float4*)&f2r[((tt) + 2) * 32 + pm4];                                        \
        }                                                                                            \
    } else {                                                                                         \
        _Pragma("unroll") for (int i = 0; i < 8; i++) {                                              \
            int v = j + i * 256;                                                                     \
            int dd = v >> 2, mc = (v & 3) * 8;                                                       \
            uint2 lo; lo.x = wreg[i].x; lo.y = wreg[i].y;                                            \
            uint2 hi; hi.x = wreg[i].z; hi.y = wreg[i].w;                                            \
            *(uint2*)&Whl[cc][dd * PLS + mc] = lo;                                                   \
            *(uint2*)&Whl[cc][dd * PLS + mc + 4] = hi;                                               \
        }                                                                                            \
        if ((tt) + 1 < NT) {                                                                         \
            _Pragma("unroll") for (int i = 0; i < 8; i++) {                                          \
                int v = j + i * 256;                                                                 \
                int dd = v >> 2, mc = (v & 3) * 8;                                                   \
                wreg[i] = *(const uint4*)&WhT[((size_t)r * D + dd) * N + ((tt) + 1) * 32 + mc];      \
            }                                                                                        \
        }                                                                                            \
    }

#define MFMASTEP(cc)                                                                                 \
    {                                                                                                \
        union UA { bf16x8_t v; uint2 u[2]; };                                                        \
        UA a[2], bb;                                                                                 \
        __builtin_amdgcn_s_setprio(1);                                                               \
        _Pragma("unroll") for (int nf = 0; nf < 2; nf++) {                                           \
            int arow = nf * 16 + rs;                                                                 \
            a[nf].u[0] = *(const uint2*)&Pl[cc][arow * PLS + 4 * g];                                 \
            a[nf].u[1] = *(const uint2*)&Pl[cc][arow * PLS + 16 + 4 * g];                            \
        }                                                                                            \
        _Pragma("unroll") for (int df = 0; df < 4; df++) {                                           \
            int brow = w * 64 + df * 16 + rs;                                                        \
            bb.u[0] = *(const uint2*)&Whl[cc][brow * PLS + 4 * g];                                   \
            bb.u[1] = *(const uint2*)&Whl[cc][brow * PLS + 16 + 4 * g];                              \
            acc[0][df] = __builtin_amdgcn_mfma_f32_16x16x32_bf16(a[0].v, bb.v, acc[0][df], 0, 0, 0); \
            acc[1][df] = __builtin_amdgcn_mfma_f32_16x16x32_bf16(a[1].v, bb.v, acc[1][df], 0, 0, 0); \
        }                                                                                            \
        __builtin_amdgcn_s_setprio(0);                                                               \
    }

    PRODUCE(0, 0, avA, fvA);
    __syncthreads();
    for (int t = 0; t < NT; t += 2) {
        if (t + 1 < NT) { PRODUCE(t + 1, 1, avB, fvB); }
        MFMASTEP(0);
        __syncthreads();
        if (t + 2 < NT) { PRODUCE(t + 2, 0, avA, fvA); }
        MFMASTEP(1);
        __syncthreads();
    }
#undef PRODUCE
#undef MFMASTEP
    // final l: reduce myl over the 8 producer threads of each row, publish, normalize, ELU, store.
    if (tid < 256) {
        float v = myl;
#pragma unroll
        for (int msk = 1; msk < 8; msk <<= 1) v += __shfl_xor(v, msk, 8);
        if ((tid & 7) == 0) sl[pn] = v;
    }
    __syncthreads();
    float inv[2][4];
#pragma unroll
    for (int nf = 0; nf < 2; nf++)
#pragma unroll
        for (int reg = 0; reg < 4; reg++) inv[nf][reg] = 1.f / sl[nf * 16 + 4 * g + reg];
#pragma unroll
    for (int nf = 0; nf < 2; nf++)
#pragma unroll
        for (int df = 0; df < 4; df++)
#pragma unroll
            for (int reg = 0; reg < 4; reg++) {
                int n = n0 + nf * 16 + 4 * g + reg;
                int d = w * 64 + df * 16 + rs;
                float v = acc[nf][df][reg] * inv[nf][reg];
                v = v > 0.f ? v : (__expf(v) - 1.f);
                stf(&xr[((size_t)r * N + n) * D + d], v);
            }
}

// ---------------- LayerNorm per (r,n) row then max over r (bf16->bf16) ----------------
__global__ __launch_bounds__(256) void k_lnmax(const bf16* __restrict__ xr, const float* __restrict__ g,
                                               const float* __restrict__ b, bf16* __restrict__ xout) {
    int n = blockIdx.x;
    int tid = threadIdx.x;
    int wave = tid >> 6, lane = tid & 63;
    __shared__ float redA[4], redB[4];
    float g0 = g[tid], g1 = g[tid + 256];
    float bb0 = b[tid], bb1 = b[tid + 256];
    float mx0 = -3e38f, mx1 = -3e38f;
    for (int r = 0; r < R; r++) {
        const bf16* row = xr + ((size_t)(r * N + n)) * D;
        float v0 = ldf(&row[tid]), v1 = ldf(&row[tid + 256]);
        float s = v0 + v1;
        float ss = fmaf(v0, v0, v1 * v1);
        s = waveReduceSum(s);
        ss = waveReduceSum(ss);
        if (lane == 0) { redA[wave] = s; redB[wave] = ss; }
        __syncthreads();
        float mu = ((redA[0] + redA[1]) + (redA[2] + redA[3])) * (1.f / D);
        float ex2 = ((redB[0] + redB[1]) + (redB[2] + redB[3])) * (1.f / D);
        float inv = 1.f / sqrtf(ex2 - mu * mu + LNEPS);
        mx0 = fmaxf(mx0, (v0 - mu) * inv * g0 + bb0);
        mx1 = fmaxf(mx1, (v1 - mu) * inv * g1 + bb1);
        __syncthreads();
    }
    stf(&xout[n * D + tid], mx0);
    stf(&xout[n * D + tid + 256], mx1);
}

// ---------------- final decoder round: max over r, f32 out ----------------
__global__ __launch_bounds__(256) void k_maxout(const bf16* __restrict__ xr, float* __restrict__ out) {
    size_t idx = (size_t)blockIdx.x * 256 + threadIdx.x;
    float m = ldf(&xr[idx]);
    m = fmaxf(m, ldf(&xr[(size_t)N * D + idx]));
    m = fmaxf(m, ldf(&xr[2 * (size_t)N * D + idx]));
    m = fmaxf(m, ldf(&xr[3 * (size_t)N * D + idx]));
    out[idx] = m;
}

// ---------------- choices head, phase 1: per-candidate dots ----------------
__global__ __launch_bounds__(256) void k_cscore(const bf16* __restrict__ xe, const int* __restrict__ cidx,
                                                const float* __restrict__ qproj, const float* __restrict__ Wout,
                                                float* __restrict__ scw, float* __restrict__ dvw) {
    int wv = threadIdx.x >> 6, lane = threadIdx.x & 63;
    int p = blockIdx.x * 4 + wv;  // 0..319 = k*64+c
    const bf16* row = xe + (size_t)cidx[p] * D;
    float s1 = 0.f, s2 = 0.f;
#pragma unroll
    for (int i = 0; i < 8; i++) {
        int d = lane + i * 64;
        float v = ldf(&row[d]);
        s1 = fmaf(v, qproj[d], s1);
        s2 = fmaf(v, Wout[d], s2);
    }
    s1 = waveReduceSum(s1);
    s2 = waveReduceSum(s2);
    if (lane == 0) { scw[p] = s1; dvw[p] = s2; }
}

// ---------------- choices head, phase 2: softmax + logits + log_softmax ----------------
__global__ __launch_bounds__(64) void k_cfinal(const float* __restrict__ scw, const float* __restrict__ dvw,
                                               const float* __restrict__ bout, float* __restrict__ out) {
    int lane = threadIdx.x;
    __shared__ float lg[5];
    for (int k = 0; k < 5; k++) {
        float v = scw[k * NC + lane];
        float m = waveReduceMax(v);
        m = __shfl(m, 0, 64);
        float e = __expf(v - m);
        float s = waveReduceSum(e);
        s = __shfl(s, 0, 64);
        float t = (e / s) * dvw[k * NC + lane];
        t = waveReduceSum(t);
        if (lane == 0) lg[k] = t + bout[0];
    }
    __syncthreads();
    if (lane == 0) {
        float m = -3e38f;
        for (int k = 0; k < 5; k++) m = fmaxf(m, lg[k]);
        float s = 0.f;
        for (int k = 0; k < 5; k++) s += __expf(lg[k] - m);
        float lse = logf(s) + m;
        for (int k = 0; k < 5; k++) out[k] = lg[k] - lse;
    }
}

extern "C" void kernel_launch(void* const* d_in, const int* in_sizes, int n_in,
                              void* d_out, int out_size, void* d_ws, size_t ws_size,
                              hipStream_t stream) {
    bool skipQ = false;
    if (n_in > 4 && in_sizes[4] != 5 * NC && in_sizes[3] == 5 * NC) skipQ = true;
    auto IN = [&](int i) -> const void* {
        int j = (skipQ && i >= 4) ? i - 1 : i;
        return d_in[j];
    };
    const float* x = (const float*)IN(0);
    const int* adj = (const int*)IN(1);
    const float* qe1 = (const float*)IN(2);
    const int* cidx = (const int*)IN(4);
    const float* Wc = (const float*)IN(5);
    const float* bc = (const float*)IN(6);
    const float* wq = (const float*)IN(7);
    const float* encW = (const float*)IN(8);
    const float* enca1 = (const float*)IN(9);
    const float* enca2 = (const float*)IN(10);
    const float* decW = (const float*)IN(11);
    const float* deca1 = (const float*)IN(12);
    const float* deca2 = (const float*)IN(13);
    const float* lng = (const float*)IN(14);
    const float* lnb = (const float*)IN(15);
    const float* Wqc = (const float*)IN(16);
    const float* bqc = (const float*)IN(17);
    const float* Wout = (const float*)IN(18);
    const float* bout = (const float*)IN(19);
    float* out = (float*)d_out;  // f32 output (proven round 6)

    // Workspace: 21,110,784 B total — round-7-proven footprint.
    char* w8 = (char*)d_ws;
    float* qemb = (float*)(w8 + 0);
    float* vvec = (float*)(w8 + 2048);
    float* qproj = (float*)(w8 + 4096);
    float* c0 = (float*)(w8 + 6144);
    float* f1 = (float*)(w8 + 8192);
    float* f2 = (float*)(w8 + 8192 + 32768);
    float* scw = (float*)(w8 + 8192 + 65536);
    float* dvw = (float*)(w8 + 8192 + 98304);
    const size_t ND = (size_t)N * D;
    bf16* xcur = (bf16*)(w8 + 139264);                       // 2 MB
    bf16* xd = (bf16*)(w8 + 139264 + ND * 2);                // 2 MB
    short* WhT = (short*)(w8 + 139264 + ND * 4);             // 8 MB
    bf16* xr = (bf16*)(w8 + 139264 + ND * 4 + R * ND * 2);   // 8 MB
    short* Wt = (short*)xr;  // per-layer bf16 weights (2 MB) alias xr; lifetimes disjoint

    k_prep<<<1, 512, 0, stream>>>(qe1, wq, Wc, bc, Wqc, bqc, qemb, vvec, qproj, c0);
    k_gate<<<N, 256, 0, stream>>>(x, vvec, qemb, c0, xcur);

    for (int L = 0; L < 4; L++) {
        const float* Wb = (L < 2) ? encW + (size_t)L * R * D * D : decW + (size_t)(L - 2) * R * D * D;
        const float* a1 = (L < 2) ? enca1 + L * R * D : deca1 + (L - 2) * R * D;
        const float* a2 = (L < 2) ? enca2 + L * R * D : deca2 + (L - 2) * R * D;
        const bf16* xin = (L == 3) ? xd : xcur;
        k_prepw<<<dim3(16, 16, R), 256, 0, stream>>>(Wb, Wt);
        k_zero12<<<R * N / 256, 256, 0, stream>>>(f1, f2);
        k_gemm_mfma<<<dim3(N / 64, D / 64, R), 256, 0, stream>>>(xin, Wt, WhT, a1, a2, f1, f2);
        k_pv_nm<<<dim3(N / 32, R), 512, 0, stream>>>(adj, f1, f2, WhT, xr);
        if (L < 3)
            k_lnmax<<<N, 256, 0, stream>>>(xr, lng, lnb, (L < 2) ? xcur : xd);
        else
            k_maxout<<<N * D / 256, 256, 0, stream>>>(xr, out + 5);
    }
    k_cscore<<<80, 256, 0, stream>>>(xcur, cidx, qproj, Wout, scw, dvw);
    k_cfinal<<<1, 64, 0, stream>>>(scw, dvw, bout, out);
}

// Round 30
// 373.223 us; speedup vs baseline: 1.3150x; 1.0306x over previous
//
#include <hip/hip_runtime.h>
#include <hip/hip_bf16.h>

typedef __hip_bfloat16 bf16;
typedef __attribute__((ext_vector_type(8))) short bf16x8_t;
typedef __attribute__((ext_vector_type(4))) float f32x4_t;

#define N 2048
#define D 512
#define R 4
#define Q 32
#define NC 64
#define ALPHA 0.2f
#define LNEPS 1e-5f
#define NEGC -9e15f
#define PLS 44  // PV LDS row stride (shorts): 22 banks, gcd(22,32)=2 -> 16 rows hit 16 distinct banks

__device__ __forceinline__ float ldf(const float* p) { return *p; }
__device__ __forceinline__ float ldf(const bf16* p) { return __bfloat162float(*p); }
__device__ __forceinline__ void stf(float* p, float v) { *p = v; }
__device__ __forceinline__ void stf(bf16* p, float v) { *p = __float2bfloat16(v); }

__device__ __forceinline__ short f2b(float f) {  // RNE float->bf16 bits
    unsigned u = __builtin_bit_cast(unsigned, f);
    unsigned r = u + 0x7FFFu + ((u >> 16) & 1u);
    return (short)(r >> 16);
}
__device__ __forceinline__ float b2fs(short s) {
    unsigned u = ((unsigned)(unsigned short)s) << 16;
    return __builtin_bit_cast(float, u);
}
__device__ __forceinline__ unsigned pk2(float a, float b) {
    return (unsigned)(unsigned short)f2b(a) | (((unsigned)(unsigned short)f2b(b)) << 16);
}

__device__ __forceinline__ float waveReduceSum(float v) {
#pragma unroll
    for (int o = 32; o > 0; o >>= 1) v += __shfl_down(v, o, 64);
    return v;
}
__device__ __forceinline__ float waveReduceMax(float v) {
#pragma unroll
    for (int o = 32; o > 0; o >>= 1) v = fmaxf(v, __shfl_down(v, o, 64));
    return v;
}

// ---------------- prep: qemb, vvec, c0, qproj ----------------
__global__ __launch_bounds__(512) void k_prep(const float* __restrict__ qe1, const float* __restrict__ wq,
                                              const float* __restrict__ Wc, const float* __restrict__ bc,
                                              const float* __restrict__ Wqc, const float* __restrict__ bqc,
                                              float* __restrict__ qemb, float* __restrict__ vvec,
                                              float* __restrict__ qproj, float* __restrict__ c0) {
    __shared__ float logits[Q];
    __shared__ float sw[Q];
    __shared__ float meanq[D];
    __shared__ float qembs[D];
    __shared__ float red8[8];
    int tid = threadIdx.x;
    int wave = tid >> 6, lane = tid & 63;
    for (int q = wave; q < Q; q += 8) {
        float s = 0.f;
        for (int d = lane; d < D; d += 64) s += qe1[q * D + d] * wq[d];
        s = waveReduceSum(s);
        if (lane == 0) logits[q] = s;
    }
    __syncthreads();
    if (tid == 0) {
        float m = -3e38f;
        for (int q = 0; q < Q; q++) m = fmaxf(m, logits[q]);
        float ssum = 0.f;
        for (int q = 0; q < Q; q++) { float e = __expf(logits[q] - m); sw[q] = e; ssum += e; }
        float inv = 1.f / ssum;
        for (int q = 0; q < Q; q++) sw[q] *= inv;
    }
    __syncthreads();
    {
        float acc = 0.f, mq = 0.f;
#pragma unroll 4
        for (int q = 0; q < Q; q++) { float xv = qe1[q * D + tid]; acc += sw[q] * xv; mq += xv; }
        qembs[tid] = acc;
        meanq[tid] = mq * (1.f / Q);
        qemb[tid] = acc;
    }
    __syncthreads();
    {
        float v = 0.f, qp = 0.f;
        for (int i = 0; i < D; i++) {
            v = fmaf(qembs[i], Wc[i * D + tid], v);
            qp = fmaf(meanq[i], Wqc[i * D + tid], qp);
        }
        vvec[tid] = v;
        qproj[tid] = qp + bqc[tid];
    }
    float cc = qembs[tid] * bc[tid];
    cc = waveReduceSum(cc);
    if (lane == 0) red8[wave] = cc;
    __syncthreads();
    if (tid == 0) {
        float t = 0.f;
        for (int i = 0; i < 8; i++) t += red8[i];
        c0[0] = t;
    }
}

// ---------------- weight prep (per layer): W[r][k][d] f32 -> Wt[r][d][k] bf16 ----------------
__global__ __launch_bounds__(256) void k_prepw(const float* __restrict__ W, short* __restrict__ Wt) {
    int mi = blockIdx.z;
    int k0 = blockIdx.y * 32, d0 = blockIdx.x * 32;
    __shared__ float L[32][33];
    int tid = threadIdx.x;
    const float* Wm = W + (size_t)mi * D * D;
    {
        int kr = tid >> 3, dc = (tid & 7) * 4;
        float4 f = *(const float4*)&Wm[(size_t)(k0 + kr) * D + d0 + dc];
        L[kr][dc] = f.x; L[kr][dc + 1] = f.y; L[kr][dc + 2] = f.z; L[kr][dc + 3] = f.w;
    }
    __syncthreads();
    short* Wo = Wt + (size_t)mi * D * D;
    {
        int dr = tid >> 3, kc = (tid & 7) * 4;
        uint2 o;
        o.x = pk2(L[kc][dr], L[kc + 1][dr]);
        o.y = pk2(L[kc + 2][dr], L[kc + 3][dr]);
        *(uint2*)&Wo[(size_t)(d0 + dr) * D + k0 + kc] = o;
    }
}

// ---------------- zero f1/f2 (per layer, before fused GEMM accumulation) ----------------
__global__ __launch_bounds__(256) void k_zero12(float* __restrict__ f1, float* __restrict__ f2) {
    int i = blockIdx.x * 256 + threadIdx.x;  // R*N = 8192
    f1[i] = 0.f;
    f2[i] = 0.f;
}

// ---------------- gate -> bf16 xcur ----------------
__global__ __launch_bounds__(256) void k_gate(const float* __restrict__ x, const float* __restrict__ vvec,
                                              const float* __restrict__ qemb, const float* __restrict__ c0,
                                              bf16* __restrict__ xcur) {
    int n = blockIdx.x;
    int tid = threadIdx.x;
    __shared__ float red[4];
    __shared__ float ps;
    float x0 = x[n * D + tid], x1 = x[n * D + tid + 256];
    float v = x0 * vvec[tid] + x1 * vvec[tid + 256];
    v = waveReduceSum(v);
    if ((tid & 63) == 0) red[tid >> 6] = v;
    __syncthreads();
    if (tid == 0) {
        float dot = (red[0] + red[1]) + (red[2] + red[3]) + c0[0];
        ps = 1.f / (1.f + __expf(-dot));
    }
    __syncthreads();
    float p = ps;
    stf(&xcur[n * D + tid], p * x0 + (1.f - p) * qemb[tid]);
    stf(&xcur[n * D + tid + 256], p * x1 + (1.f - p) * qemb[tid + 256]);
}

// ---------------- MFMA GEMM + fused f1/f2: WhT[r][d][m] = (xin @ W[r])^T bf16 ----------------
__global__ __launch_bounds__(256) void k_gemm_mfma(const bf16* __restrict__ xin, const short* __restrict__ Wt,
                                                   short* __restrict__ WhT, const float* __restrict__ a1b,
                                                   const float* __restrict__ a2b, float* __restrict__ f1,
                                                   float* __restrict__ f2) {
    int r = blockIdx.z;
    int m0 = blockIdx.x * 64;
    int d0 = blockIdx.y * 64;
    int tid = threadIdx.x;
    int w = tid >> 6, l = tid & 63, g = l >> 4, rs = l & 15;
    int wn = w >> 1, wd = w & 1;
    __shared__ __align__(16) short Al[64 * 40];
    __shared__ __align__(16) short Bl[64 * 40];
    __shared__ __align__(16) short Tt[64 * 80];
    __shared__ float a1s[64], a2s[64];
    __shared__ float r1[4][64], r2[4][64];
    if (tid < 64) {
        a1s[tid] = a1b[r * D + d0 + tid];
        a2s[tid] = a2b[r * D + d0 + tid];
    }
    f32x4_t acc[2][2];
#pragma unroll
    for (int i = 0; i < 2; i++)
#pragma unroll
        for (int j = 0; j < 2; j++) acc[i][j] = (f32x4_t)(0.0f);

    const short* Wtr = Wt + (size_t)r * D * D;
    int sn = tid >> 2;
    int sk = (tid & 3) * 8;
    for (int k0 = 0; k0 < D; k0 += 32) {
        __syncthreads();
        {
            *(uint4*)&Al[sn * 40 + sk] = *(const uint4*)&xin[(size_t)(m0 + sn) * D + k0 + sk];
            *(uint4*)&Bl[sn * 40 + sk] = *(const uint4*)&Wtr[(size_t)(d0 + sn) * D + k0 + sk];
        }
        __syncthreads();
        union UA { bf16x8_t v; uint2 u[2]; };
        UA a[2], b;
#pragma unroll
        for (int nf = 0; nf < 2; nf++) {
            int arow = wn * 32 + nf * 16 + rs;
            a[nf].u[0] = *(const uint2*)&Al[arow * 40 + 4 * g];
            a[nf].u[1] = *(const uint2*)&Al[arow * 40 + 16 + 4 * g];
        }
#pragma unroll
        for (int df = 0; df < 2; df++) {
            int brow = wd * 32 + df * 16 + rs;
            b.u[0] = *(const uint2*)&Bl[brow * 40 + 4 * g];
            b.u[1] = *(const uint2*)&Bl[brow * 40 + 16 + 4 * g];
            acc[0][df] = __builtin_amdgcn_mfma_f32_16x16x32_bf16(a[0].v, b.v, acc[0][df], 0, 0, 0);
            acc[1][df] = __builtin_amdgcn_mfma_f32_16x16x32_bf16(a[1].v, b.v, acc[1][df], 0, 0, 0);
        }
    }
    __syncthreads();
    // D layout (m89): col(lane&15)->d, row(4*(lane>>4)+reg)->m. Stage Tt[d][m], coalesced store.
#pragma unroll
    for (int nf = 0; nf < 2; nf++)
#pragma unroll
        for (int df = 0; df < 2; df++) {
            int nl = wn * 32 + nf * 16 + 4 * g;
            int dl = wd * 32 + df * 16 + rs;
            uint2 o;
            o.x = pk2(acc[nf][df][0], acc[nf][df][1]);
            o.y = pk2(acc[nf][df][2], acc[nf][df][3]);
            *(uint2*)&Tt[dl * 80 + nl] = o;
        }
    __syncthreads();
    {
        int dl = tid >> 2;
        int nc = (tid & 3) * 16;
        uint4 v0 = *(const uint4*)&Tt[dl * 80 + nc];
        uint4 v1 = *(const uint4*)&Tt[dl * 80 + nc + 8];
        short* op = WhT + ((size_t)r * D + d0 + dl) * N + m0 + nc;
        *(uint4*)op = v0;
        *(uint4*)(op + 8) = v1;
    }
    // fused f1/f2 partials from Tt (same bf16 values k_f12t would have read)
    {
        int m = tid & 63, dg = tid >> 6;
        float s1 = 0.f, s2 = 0.f;
#pragma unroll
        for (int d = 0; d < 16; d++) {
            int dd = dg + d * 4;
            float wv = b2fs(Tt[dd * 80 + m]);
            s1 = fmaf(wv, a1s[dd], s1);
            s2 = fmaf(wv, a2s[dd], s2);
        }
        r1[dg][m] = s1;
        r2[dg][m] = s2;
    }
    __syncthreads();
    if (tid < 64) {
        float v1 = (r1[0][tid] + r1[1][tid]) + (r1[2][tid] + r1[3][tid]);
        float v2 = (r2[0][tid] + r2[1][tid]) + (r2[2][tid] + r2[3][tid]);
        atomicAdd(&f1[r * N + m0 + tid], v1);
        atomicAdd(&f2[r * N + m0 + tid], v2);
    }
}

// ---------------- fused PV: no-max softmax, depth-2 producer, stager wreg prefetch (r26 best) ----
__global__ __launch_bounds__(512, 2) void k_pv_nm(const int* __restrict__ adj, const float* __restrict__ f1,
                                                  const float* __restrict__ f2, const short* __restrict__ WhT,
                                                  bf16* __restrict__ xr) {
    int r = blockIdx.y;
    int n0 = blockIdx.x * 32;
    int tid = threadIdx.x;
    int w = tid >> 6, l = tid & 63, g = l >> 4, rs = l & 15;
    __shared__ __align__(16) short Pl[2][32 * PLS];
    __shared__ __align__(16) short Whl[2][512 * PLS];
    __shared__ float sl[32], f1s[32];
    if (tid < 32) f1s[tid] = f1[r * N + n0 + tid];
    __syncthreads();
    f32x4_t acc[2][4];
#pragma unroll
    for (int i = 0; i < 2; i++)
#pragma unroll
        for (int j = 0; j < 4; j++) acc[i][j] = (f32x4_t)(0.0f);

    int pn = tid >> 3, pm4 = (tid & 7) * 4;
    const float* f2r = f2 + r * N;
    const int* arowb = adj + ((size_t)r * N + n0 + (pn & 31)) * N + pm4;
    int4 avA, avB;
    float4 fvA, fvB;
    float f1v = 0.f;
    float myl = 0.f;
    int j = tid - 256;
    uint4 wreg[8];
    if (tid < 256) {
        f1v = f1s[pn];
        avA = *(const int4*)(arowb);
        fvA = *(const float4*)&f2r[pm4];
        avB = *(const int4*)(arowb + 32);
        fvB = *(const float4*)&f2r[32 + pm4];
    } else {
        // prologue: load tile 0 into wreg
#pragma unroll
        for (int i = 0; i < 8; i++) {
            int v = j + i * 256;
            int dd = v >> 2, mc = (v & 3) * 8;
            wreg[i] = *(const uint4*)&WhT[((size_t)r * D + dd) * N + mc];
        }
    }

    const int NT = N / 32;  // 64 (even)

    // PRODUCE(tile tt -> buffer cc): producer computes P(tt) w/ depth-2 adj prefetch;
    // stager writes wreg (tile tt) to Whl[cc], then loads tile tt+1 into wreg.
#define PRODUCE(tt, cc, AV, FV)                                                                      \
    if (tid < 256) {                                                                                 \
        float t0 = f1v + FV.x; t0 = t0 >= 0.f ? t0 : ALPHA * t0;                                     \
        float t1 = f1v + FV.y; t1 = t1 >= 0.f ? t1 : ALPHA * t1;                                     \
        float t2 = f1v + FV.z; t2 = t2 >= 0.f ? t2 : ALPHA * t2;                                     \
        float t3 = f1v + FV.w; t3 = t3 >= 0.f ? t3 : ALPHA * t3;                                     \
        float e0 = (AV.x > 0) ? __expf(fminf(t0, 60.f)) : 0.f;                                       \
        float e1 = (AV.y > 0) ? __expf(fminf(t1, 60.f)) : 0.f;                                       \
        float e2 = (AV.z > 0) ? __expf(fminf(t2, 60.f)) : 0.f;                                       \
        float e3 = (AV.w > 0) ? __expf(fminf(t3, 60.f)) : 0.f;                                       \
        myl += (e0 + e1) + (e2 + e3);                                                                \
        uint2 pw;                                                                                    \
        pw.x = pk2(e0, e1);                                                                          \
        pw.y = pk2(e2, e3);                                                                          \
        *(uint2*)&Pl[cc][pn * PLS + pm4] = pw;                                                       \
        if ((tt) + 2 < NT) {                                                                         \
            AV = *(const int4*)(arowb + ((tt) + 2) * 32);                                            \
            FV = *(const float4*)&f2r[((tt) + 2) * 32 + pm4];                                        \
        }                                                                                            \
    } else {                                                                                         \
        _Pragma("unroll") for (int i = 0; i < 8; i++) {                                              \
            int v = j + i * 256;                                                                     \
            int dd = v >> 2, mc = (v & 3) * 8;                                                       \
            uint2 lo; lo.x = wreg[i].x; lo.y = wreg[i].y;                                            \
            uint2 hi; hi.x = wreg[i].z; hi.y = wreg[i].w;                                            \
            *(uint2*)&Whl[cc][dd * PLS + mc] = lo;                                                   \
            *(uint2*)&Whl[cc][dd * PLS + mc + 4] = hi;                                               \
        }                                                                                            \
        if ((tt) + 1 < NT) {                                                                         \
            _Pragma("unroll") for (int i = 0; i < 8; i++) {                                          \
                int v = j + i * 256;                                                                 \
                int dd = v >> 2, mc = (v & 3) * 8;                                                   \
                wreg[i] = *(const uint4*)&WhT[((size_t)r * D + dd) * N + ((tt) + 1) * 32 + mc];      \
            }                                                                                        \
        }                                                                                            \
    }

#define MFMASTEP(cc)                                                                                 \
    {                                                                                                \
        union UA { bf16x8_t v; uint2 u[2]; };                                                        \
        UA a[2], bb;                                                                                 \
        _Pragma("unroll") for (int nf = 0; nf < 2; nf++) {                                           \
            int arow = nf * 16 + rs;                                                                 \
            a[nf].u[0] = *(const uint2*)&Pl[cc][arow * PLS + 4 * g];                                 \
            a[nf].u[1] = *(const uint2*)&Pl[cc][arow * PLS + 16 + 4 * g];                            \
        }                                                                                            \
        _Pragma("unroll") for (int df = 0; df < 4; df++) {                                           \
            int brow = w * 64 + df * 16 + rs;                                                        \
            bb.u[0] = *(const uint2*)&Whl[cc][brow * PLS + 4 * g];                                   \
            bb.u[1] = *(const uint2*)&Whl[cc][brow * PLS + 16 + 4 * g];                              \
            acc[0][df] = __builtin_amdgcn_mfma_f32_16x16x32_bf16(a[0].v, bb.v, acc[0][df], 0, 0, 0); \
            acc[1][df] = __builtin_amdgcn_mfma_f32_16x16x32_bf16(a[1].v, bb.v, acc[1][df], 0, 0, 0); \
        }                                                                                            \
    }

    PRODUCE(0, 0, avA, fvA);
    __syncthreads();
    for (int t = 0; t < NT; t += 2) {
        if (t + 1 < NT) { PRODUCE(t + 1, 1, avB, fvB); }
        MFMASTEP(0);
        __syncthreads();
        if (t + 2 < NT) { PRODUCE(t + 2, 0, avA, fvA); }
        MFMASTEP(1);
        __syncthreads();
    }
#undef PRODUCE
#undef MFMASTEP
    // final l: reduce myl over the 8 producer threads of each row, publish, normalize, ELU, store.
    if (tid < 256) {
        float v = myl;
#pragma unroll
        for (int msk = 1; msk < 8; msk <<= 1) v += __shfl_xor(v, msk, 8);
        if ((tid & 7) == 0) sl[pn] = v;
    }
    __syncthreads();
    float inv[2][4];
#pragma unroll
    for (int nf = 0; nf < 2; nf++)
#pragma unroll
        for (int reg = 0; reg < 4; reg++) inv[nf][reg] = 1.f / sl[nf * 16 + 4 * g + reg];
#pragma unroll
    for (int nf = 0; nf < 2; nf++)
#pragma unroll
        for (int df = 0; df < 4; df++)
#pragma unroll
            for (int reg = 0; reg < 4; reg++) {
                int n = n0 + nf * 16 + 4 * g + reg;
                int d = w * 64 + df * 16 + rs;
                float v = acc[nf][df][reg] * inv[nf][reg];
                v = v > 0.f ? v : (__expf(v) - 1.f);
                stf(&xr[((size_t)r * N + n) * D + d], v);
            }
}

// ---------------- LayerNorm per (r,n) row then max over r (bf16->bf16) ----------------
__global__ __launch_bounds__(256) void k_lnmax(const bf16* __restrict__ xr, const float* __restrict__ g,
                                               const float* __restrict__ b, bf16* __restrict__ xout) {
    int n = blockIdx.x;
    int tid = threadIdx.x;
    int wave = tid >> 6, lane = tid & 63;
    __shared__ float redA[4], redB[4];
    float g0 = g[tid], g1 = g[tid + 256];
    float bb0 = b[tid], bb1 = b[tid + 256];
    float mx0 = -3e38f, mx1 = -3e38f;
    for (int r = 0; r < R; r++) {
        const bf16* row = xr + ((size_t)(r * N + n)) * D;
        float v0 = ldf(&row[tid]), v1 = ldf(&row[tid + 256]);
        float s = v0 + v1;
        float ss = fmaf(v0, v0, v1 * v1);
        s = waveReduceSum(s);
        ss = waveReduceSum(ss);
        if (lane == 0) { redA[wave] = s; redB[wave] = ss; }
        __syncthreads();
        float mu = ((redA[0] + redA[1]) + (redA[2] + redA[3])) * (1.f / D);
        float ex2 = ((redB[0] + redB[1]) + (redB[2] + redB[3])) * (1.f / D);
        float inv = 1.f / sqrtf(ex2 - mu * mu + LNEPS);
        mx0 = fmaxf(mx0, (v0 - mu) * inv * g0 + bb0);
        mx1 = fmaxf(mx1, (v1 - mu) * inv * g1 + bb1);
        __syncthreads();
    }
    stf(&xout[n * D + tid], mx0);
    stf(&xout[n * D + tid + 256], mx1);
}

// ---------------- final decoder round: max over r, f32 out ----------------
__global__ __launch_bounds__(256) void k_maxout(const bf16* __restrict__ xr, float* __restrict__ out) {
    size_t idx = (size_t)blockIdx.x * 256 + threadIdx.x;
    float m = ldf(&xr[idx]);
    m = fmaxf(m, ldf(&xr[(size_t)N * D + idx]));
    m = fmaxf(m, ldf(&xr[2 * (size_t)N * D + idx]));
    m = fmaxf(m, ldf(&xr[3 * (size_t)N * D + idx]));
    out[idx] = m;
}

// ---------------- choices head, phase 1: per-candidate dots ----------------
__global__ __launch_bounds__(256) void k_cscore(const bf16* __restrict__ xe, const int* __restrict__ cidx,
                                                const float* __restrict__ qproj, const float* __restrict__ Wout,
                                                float* __restrict__ scw, float* __restrict__ dvw) {
    int wv = threadIdx.x >> 6, lane = threadIdx.x & 63;
    int p = blockIdx.x * 4 + wv;  // 0..319 = k*64+c
    const bf16* row = xe + (size_t)cidx[p] * D;
    float s1 = 0.f, s2 = 0.f;
#pragma unroll
    for (int i = 0; i < 8; i++) {
        int d = lane + i * 64;
        float v = ldf(&row[d]);
        s1 = fmaf(v, qproj[d], s1);
        s2 = fmaf(v, Wout[d], s2);
    }
    s1 = waveReduceSum(s1);
    s2 = waveReduceSum(s2);
    if (lane == 0) { scw[p] = s1; dvw[p] = s2; }
}

// ---------------- choices head, phase 2: softmax + logits + log_softmax ----------------
__global__ __launch_bounds__(64) void k_cfinal(const float* __restrict__ scw, const float* __restrict__ dvw,
                                               const float* __restrict__ bout, float* __restrict__ out) {
    int lane = threadIdx.x;
    __shared__ float lg[5];
    for (int k = 0; k < 5; k++) {
        float v = scw[k * NC + lane];
        float m = waveReduceMax(v);
        m = __shfl(m, 0, 64);
        float e = __expf(v - m);
        float s = waveReduceSum(e);
        s = __shfl(s, 0, 64);
        float t = (e / s) * dvw[k * NC + lane];
        t = waveReduceSum(t);
        if (lane == 0) lg[k] = t + bout[0];
    }
    __syncthreads();
    if (lane == 0) {
        float m = -3e38f;
        for (int k = 0; k < 5; k++) m = fmaxf(m, lg[k]);
        float s = 0.f;
        for (int k = 0; k < 5; k++) s += __expf(lg[k] - m);
        float lse = logf(s) + m;
        for (int k = 0; k < 5; k++) out[k] = lg[k] - lse;
    }
}

extern "C" void kernel_launch(void* const* d_in, const int* in_sizes, int n_in,
                              void* d_out, int out_size, void* d_ws, size_t ws_size,
                              hipStream_t stream) {
    bool skipQ = false;
    if (n_in > 4 && in_sizes[4] != 5 * NC && in_sizes[3] == 5 * NC) skipQ = true;
    auto IN = [&](int i) -> const void* {
        int j = (skipQ && i >= 4) ? i - 1 : i;
        return d_in[j];
    };
    const float* x = (const float*)IN(0);
    const int* adj = (const int*)IN(1);
    const float* qe1 = (const float*)IN(2);
    const int* cidx = (const int*)IN(4);
    const float* Wc = (const float*)IN(5);
    const float* bc = (const float*)IN(6);
    const float* wq = (const float*)IN(7);
    const float* encW = (const float*)IN(8);
    const float* enca1 = (const float*)IN(9);
    const float* enca2 = (const float*)IN(10);
    const float* decW = (const float*)IN(11);
    const float* deca1 = (const float*)IN(12);
    const float* deca2 = (const float*)IN(13);
    const float* lng = (const float*)IN(14);
    const float* lnb = (const float*)IN(15);
    const float* Wqc = (const float*)IN(16);
    const float* bqc = (const float*)IN(17);
    const float* Wout = (const float*)IN(18);
    const float* bout = (const float*)IN(19);
    float* out = (float*)d_out;  // f32 output (proven round 6)

    // Workspace: 21,110,784 B total — round-7-proven footprint.
    char* w8 = (char*)d_ws;
    float* qemb = (float*)(w8 + 0);
    float* vvec = (float*)(w8 + 2048);
    float* qproj = (float*)(w8 + 4096);
    float* c0 = (float*)(w8 + 6144);
    float* f1 = (float*)(w8 + 8192);
    float* f2 = (float*)(w8 + 8192 + 32768);
    float* scw = (float*)(w8 + 8192 + 65536);
    float* dvw = (float*)(w8 + 8192 + 98304);
    const size_t ND = (size_t)N * D;
    bf16* xcur = (bf16*)(w8 + 139264);                       // 2 MB
    bf16* xd = (bf16*)(w8 + 139264 + ND * 2);                // 2 MB
    short* WhT = (short*)(w8 + 139264 + ND * 4);             // 8 MB
    bf16* xr = (bf16*)(w8 + 139264 + ND * 4 + R * ND * 2);   // 8 MB
    short* Wt = (short*)xr;  // per-layer bf16 weights (2 MB) alias xr; lifetimes disjoint

    k_prep<<<1, 512, 0, stream>>>(qe1, wq, Wc, bc, Wqc, bqc, qemb, vvec, qproj, c0);
    k_gate<<<N, 256, 0, stream>>>(x, vvec, qemb, c0, xcur);

    for (int L = 0; L < 4; L++) {
        const float* Wb = (L < 2) ? encW + (size_t)L * R * D * D : decW + (size_t)(L - 2) * R * D * D;
        const float* a1 = (L < 2) ? enca1 + L * R * D : deca1 + (L - 2) * R * D;
        const float* a2 = (L < 2) ? enca2 + L * R * D : deca2 + (L - 2) * R * D;
        const bf16* xin = (L == 3) ? xd : xcur;
        k_prepw<<<dim3(16, 16, R), 256, 0, stream>>>(Wb, Wt);
        k_zero12<<<R * N / 256, 256, 0, stream>>>(f1, f2);
        k_gemm_mfma<<<dim3(N / 64, D / 64, R), 256, 0, stream>>>(xin, Wt, WhT, a1, a2, f1, f2);
        k_pv_nm<<<dim3(N / 32, R), 512, 0, stream>>>(adj, f1, f2, WhT, xr);
        if (L < 3)
            k_lnmax<<<N, 256, 0, stream>>>(xr, lng, lnb, (L < 2) ? xcur : xd);
        else
            k_maxout<<<N * D / 256, 256, 0, stream>>>(xr, out + 5);
    }
    k_cscore<<<80, 256, 0, stream>>>(xcur, cidx, qproj, Wout, scw, dvw);
    k_cfinal<<<1, 64, 0, stream>>>(scw, dvw, bout, out);
}

// Round 31
// 367.342 us; speedup vs baseline: 1.3360x; 1.0160x over previous
//
#include <hip/hip_runtime.h>
#include <hip/hip_bf16.h>

typedef __hip_bfloat16 bf16;
typedef __attribute__((ext_vector_type(8))) short bf16x8_t;
typedef __attribute__((ext_vector_type(4))) float f32x4_t;

#define N 2048
#define D 512
#define R 4
#define Q 32
#define NC 64
#define ALPHA 0.2f
#define LNEPS 1e-5f
#define NEGC -9e15f
#define PLS 44  // PV LDS row stride (shorts): 22 banks, gcd(22,32)=2 -> 16 rows hit 16 distinct banks

__device__ __forceinline__ float ldf(const float* p) { return *p; }
__device__ __forceinline__ float ldf(const bf16* p) { return __bfloat162float(*p); }
__device__ __forceinline__ void stf(float* p, float v) { *p = v; }
__device__ __forceinline__ void stf(bf16* p, float v) { *p = __float2bfloat16(v); }

__device__ __forceinline__ short f2b(float f) {  // RNE float->bf16 bits
    unsigned u = __builtin_bit_cast(unsigned, f);
    unsigned r = u + 0x7FFFu + ((u >> 16) & 1u);
    return (short)(r >> 16);
}
__device__ __forceinline__ float b2fs(short s) {
    unsigned u = ((unsigned)(unsigned short)s) << 16;
    return __builtin_bit_cast(float, u);
}
__device__ __forceinline__ unsigned pk2(float a, float b) {
    return (unsigned)(unsigned short)f2b(a) | (((unsigned)(unsigned short)f2b(b)) << 16);
}

__device__ __forceinline__ float waveReduceSum(float v) {
#pragma unroll
    for (int o = 32; o > 0; o >>= 1) v += __shfl_down(v, o, 64);
    return v;
}
__device__ __forceinline__ float waveReduceMax(float v) {
#pragma unroll
    for (int o = 32; o > 0; o >>= 1) v = fmaxf(v, __shfl_down(v, o, 64));
    return v;
}

// ---------------- prep: qemb, vvec, c0, qproj ----------------
__global__ __launch_bounds__(512) void k_prep(const float* __restrict__ qe1, const float* __restrict__ wq,
                                              const float* __restrict__ Wc, const float* __restrict__ bc,
                                              const float* __restrict__ Wqc, const float* __restrict__ bqc,
                                              float* __restrict__ qemb, float* __restrict__ vvec,
                                              float* __restrict__ qproj, float* __restrict__ c0) {
    __shared__ float logits[Q];
    __shared__ float sw[Q];
    __shared__ float meanq[D];
    __shared__ float qembs[D];
    __shared__ float red8[8];
    int tid = threadIdx.x;
    int wave = tid >> 6, lane = tid & 63;
    for (int q = wave; q < Q; q += 8) {
        float s = 0.f;
        for (int d = lane; d < D; d += 64) s += qe1[q * D + d] * wq[d];
        s = waveReduceSum(s);
        if (lane == 0) logits[q] = s;
    }
    __syncthreads();
    if (tid == 0) {
        float m = -3e38f;
        for (int q = 0; q < Q; q++) m = fmaxf(m, logits[q]);
        float ssum = 0.f;
        for (int q = 0; q < Q; q++) { float e = __expf(logits[q] - m); sw[q] = e; ssum += e; }
        float inv = 1.f / ssum;
        for (int q = 0; q < Q; q++) sw[q] *= inv;
    }
    __syncthreads();
    {
        float acc = 0.f, mq = 0.f;
#pragma unroll 4
        for (int q = 0; q < Q; q++) { float xv = qe1[q * D + tid]; acc += sw[q] * xv; mq += xv; }
        qembs[tid] = acc;
        meanq[tid] = mq * (1.f / Q);
        qemb[tid] = acc;
    }
    __syncthreads();
    {
        float v = 0.f, qp = 0.f;
        for (int i = 0; i < D; i++) {
            v = fmaf(qembs[i], Wc[i * D + tid], v);
            qp = fmaf(meanq[i], Wqc[i * D + tid], qp);
        }
        vvec[tid] = v;
        qproj[tid] = qp + bqc[tid];
    }
    float cc = qembs[tid] * bc[tid];
    cc = waveReduceSum(cc);
    if (lane == 0) red8[wave] = cc;
    __syncthreads();
    if (tid == 0) {
        float t = 0.f;
        for (int i = 0; i < 8; i++) t += red8[i];
        c0[0] = t;
    }
}

// ---------------- weight prep (per layer): W[r][k][d] f32 -> Wt[r][d][k] bf16; by==0 zeroes f1/f2 ----
__global__ __launch_bounds__(256) void k_prepw(const float* __restrict__ W, short* __restrict__ Wt,
                                               float* __restrict__ f1, float* __restrict__ f2) {
    int mi = blockIdx.z;
    int k0 = blockIdx.y * 32, d0 = blockIdx.x * 32;
    __shared__ float L[32][33];
    int tid = threadIdx.x;
    // fused k_zero12: 16 bx-blocks x 128 elems = N per r (runs before k_gemm_mfma's atomicAdds)
    if (blockIdx.y == 0 && tid < 128) {
        int base = mi * N + blockIdx.x * 128 + tid;
        f1[base] = 0.f;
        f2[base] = 0.f;
    }
    const float* Wm = W + (size_t)mi * D * D;
    {
        int kr = tid >> 3, dc = (tid & 7) * 4;
        float4 f = *(const float4*)&Wm[(size_t)(k0 + kr) * D + d0 + dc];
        L[kr][dc] = f.x; L[kr][dc + 1] = f.y; L[kr][dc + 2] = f.z; L[kr][dc + 3] = f.w;
    }
    __syncthreads();
    short* Wo = Wt + (size_t)mi * D * D;
    {
        int dr = tid >> 3, kc = (tid & 7) * 4;
        uint2 o;
        o.x = pk2(L[kc][dr], L[kc + 1][dr]);
        o.y = pk2(L[kc + 2][dr], L[kc + 3][dr]);
        *(uint2*)&Wo[(size_t)(d0 + dr) * D + k0 + kc] = o;
    }
}

// ---------------- gate -> bf16 xcur ----------------
__global__ __launch_bounds__(256) void k_gate(const float* __restrict__ x, const float* __restrict__ vvec,
                                              const float* __restrict__ qemb, const float* __restrict__ c0,
                                              bf16* __restrict__ xcur) {
    int n = blockIdx.x;
    int tid = threadIdx.x;
    __shared__ float red[4];
    __shared__ float ps;
    float x0 = x[n * D + tid], x1 = x[n * D + tid + 256];
    float v = x0 * vvec[tid] + x1 * vvec[tid + 256];
    v = waveReduceSum(v);
    if ((tid & 63) == 0) red[tid >> 6] = v;
    __syncthreads();
    if (tid == 0) {
        float dot = (red[0] + red[1]) + (red[2] + red[3]) + c0[0];
        ps = 1.f / (1.f + __expf(-dot));
    }
    __syncthreads();
    float p = ps;
    stf(&xcur[n * D + tid], p * x0 + (1.f - p) * qemb[tid]);
    stf(&xcur[n * D + tid + 256], p * x1 + (1.f - p) * qemb[tid + 256]);
}

// ---------------- MFMA GEMM + fused f1/f2: WhT[r][d][m] = (xin @ W[r])^T bf16 ----------------
__global__ __launch_bounds__(256) void k_gemm_mfma(const bf16* __restrict__ xin, const short* __restrict__ Wt,
                                                   short* __restrict__ WhT, const float* __restrict__ a1b,
                                                   const float* __restrict__ a2b, float* __restrict__ f1,
                                                   float* __restrict__ f2) {
    int r = blockIdx.z;
    int m0 = blockIdx.x * 64;
    int d0 = blockIdx.y * 64;
    int tid = threadIdx.x;
    int w = tid >> 6, l = tid & 63, g = l >> 4, rs = l & 15;
    int wn = w >> 1, wd = w & 1;
    __shared__ __align__(16) short Al[64 * 40];
    __shared__ __align__(16) short Bl[64 * 40];
    __shared__ __align__(16) short Tt[64 * 80];
    __shared__ float a1s[64], a2s[64];
    __shared__ float r1[4][64], r2[4][64];
    if (tid < 64) {
        a1s[tid] = a1b[r * D + d0 + tid];
        a2s[tid] = a2b[r * D + d0 + tid];
    }
    f32x4_t acc[2][2];
#pragma unroll
    for (int i = 0; i < 2; i++)
#pragma unroll
        for (int j = 0; j < 2; j++) acc[i][j] = (f32x4_t)(0.0f);

    const short* Wtr = Wt + (size_t)r * D * D;
    int sn = tid >> 2;
    int sk = (tid & 3) * 8;
    for (int k0 = 0; k0 < D; k0 += 32) {
        __syncthreads();
        {
            *(uint4*)&Al[sn * 40 + sk] = *(const uint4*)&xin[(size_t)(m0 + sn) * D + k0 + sk];
            *(uint4*)&Bl[sn * 40 + sk] = *(const uint4*)&Wtr[(size_t)(d0 + sn) * D + k0 + sk];
        }
        __syncthreads();
        union UA { bf16x8_t v; uint2 u[2]; };
        UA a[2], b;
#pragma unroll
        for (int nf = 0; nf < 2; nf++) {
            int arow = wn * 32 + nf * 16 + rs;
            a[nf].u[0] = *(const uint2*)&Al[arow * 40 + 4 * g];
            a[nf].u[1] = *(const uint2*)&Al[arow * 40 + 16 + 4 * g];
        }
#pragma unroll
        for (int df = 0; df < 2; df++) {
            int brow = wd * 32 + df * 16 + rs;
            b.u[0] = *(const uint2*)&Bl[brow * 40 + 4 * g];
            b.u[1] = *(const uint2*)&Bl[brow * 40 + 16 + 4 * g];
            acc[0][df] = __builtin_amdgcn_mfma_f32_16x16x32_bf16(a[0].v, b.v, acc[0][df], 0, 0, 0);
            acc[1][df] = __builtin_amdgcn_mfma_f32_16x16x32_bf16(a[1].v, b.v, acc[1][df], 0, 0, 0);
        }
    }
    __syncthreads();
    // D layout (m89): col(lane&15)->d, row(4*(lane>>4)+reg)->m. Stage Tt[d][m], coalesced store.
#pragma unroll
    for (int nf = 0; nf < 2; nf++)
#pragma unroll
        for (int df = 0; df < 2; df++) {
            int nl = wn * 32 + nf * 16 + 4 * g;
            int dl = wd * 32 + df * 16 + rs;
            uint2 o;
            o.x = pk2(acc[nf][df][0], acc[nf][df][1]);
            o.y = pk2(acc[nf][df][2], acc[nf][df][3]);
            *(uint2*)&Tt[dl * 80 + nl] = o;
        }
    __syncthreads();
    {
        int dl = tid >> 2;
        int nc = (tid & 3) * 16;
        uint4 v0 = *(const uint4*)&Tt[dl * 80 + nc];
        uint4 v1 = *(const uint4*)&Tt[dl * 80 + nc + 8];
        short* op = WhT + ((size_t)r * D + d0 + dl) * N + m0 + nc;
        *(uint4*)op = v0;
        *(uint4*)(op + 8) = v1;
    }
    // fused f1/f2 partials from Tt (same bf16 values k_f12t would have read)
    {
        int m = tid & 63, dg = tid >> 6;
        float s1 = 0.f, s2 = 0.f;
#pragma unroll
        for (int d = 0; d < 16; d++) {
            int dd = dg + d * 4;
            float wv = b2fs(Tt[dd * 80 + m]);
            s1 = fmaf(wv, a1s[dd], s1);
            s2 = fmaf(wv, a2s[dd], s2);
        }
        r1[dg][m] = s1;
        r2[dg][m] = s2;
    }
    __syncthreads();
    if (tid < 64) {
        float v1 = (r1[0][tid] + r1[1][tid]) + (r1[2][tid] + r1[3][tid]);
        float v2 = (r2[0][tid] + r2[1][tid]) + (r2[2][tid] + r2[3][tid]);
        atomicAdd(&f1[r * N + m0 + tid], v1);
        atomicAdd(&f2[r * N + m0 + tid], v2);
    }
}

// ---------------- fused PV: no-max softmax, depth-2 producer, stager wreg prefetch (r26 best) ----
__global__ __launch_bounds__(512, 2) void k_pv_nm(const int* __restrict__ adj, const float* __restrict__ f1,
                                                  const float* __restrict__ f2, const short* __restrict__ WhT,
                                                  bf16* __restrict__ xr) {
    int r = blockIdx.y;
    int n0 = blockIdx.x * 32;
    int tid = threadIdx.x;
    int w = tid >> 6, l = tid & 63, g = l >> 4, rs = l & 15;
    __shared__ __align__(16) short Pl[2][32 * PLS];
    __shared__ __align__(16) short Whl[2][512 * PLS];
    __shared__ float sl[32], f1s[32];
    if (tid < 32) f1s[tid] = f1[r * N + n0 + tid];
    __syncthreads();
    f32x4_t acc[2][4];
#pragma unroll
    for (int i = 0; i < 2; i++)
#pragma unroll
        for (int j = 0; j < 4; j++) acc[i][j] = (f32x4_t)(0.0f);

    int pn = tid >> 3, pm4 = (tid & 7) * 4;
    const float* f2r = f2 + r * N;
    const int* arowb = adj + ((size_t)r * N + n0 + (pn & 31)) * N + pm4;
    int4 avA, avB;
    float4 fvA, fvB;
    float f1v = 0.f;
    float myl = 0.f;
    int j = tid - 256;
    uint4 wreg[8];
    if (tid < 256) {
        f1v = f1s[pn];
        avA = *(const int4*)(arowb);
        fvA = *(const float4*)&f2r[pm4];
        avB = *(const int4*)(arowb + 32);
        fvB = *(const float4*)&f2r[32 + pm4];
    } else {
        // prologue: load tile 0 into wreg
#pragma unroll
        for (int i = 0; i < 8; i++) {
            int v = j + i * 256;
            int dd = v >> 2, mc = (v & 3) * 8;
            wreg[i] = *(const uint4*)&WhT[((size_t)r * D + dd) * N + mc];
        }
    }

    const int NT = N / 32;  // 64 (even)

    // PRODUCE(tile tt -> buffer cc): producer computes P(tt) w/ depth-2 adj prefetch;
    // stager writes wreg (tile tt) to Whl[cc], then loads tile tt+1 into wreg.
#define PRODUCE(tt, cc, AV, FV)                                                                      \
    if (tid < 256) {                                                                                 \
        float t0 = f1v + FV.x; t0 = t0 >= 0.f ? t0 : ALPHA * t0;                                     \
        float t1 = f1v + FV.y; t1 = t1 >= 0.f ? t1 : ALPHA * t1;                                     \
        float t2 = f1v + FV.z; t2 = t2 >= 0.f ? t2 : ALPHA * t2;                                     \
        float t3 = f1v + FV.w; t3 = t3 >= 0.f ? t3 : ALPHA * t3;                                     \
        float e0 = (AV.x > 0) ? __expf(fminf(t0, 60.f)) : 0.f;                                       \
        float e1 = (AV.y > 0) ? __expf(fminf(t1, 60.f)) : 0.f;                                       \
        float e2 = (AV.z > 0) ? __expf(fminf(t2, 60.f)) : 0.f;                                       \
        float e3 = (AV.w > 0) ? __expf(fminf(t3, 60.f)) : 0.f;                                       \
        myl += (e0 + e1) + (e2 + e3);                                                                \
        uint2 pw;                                                                                    \
        pw.x = pk2(e0, e1);                                                                          \
        pw.y = pk2(e2, e3);                                                                          \
        *(uint2*)&Pl[cc][pn * PLS + pm4] = pw;                                                       \
        if ((tt) + 2 < NT) {                                                                         \
            AV = *(const int4*)(arowb + ((tt) + 2) * 32);                                            \
            FV = *(const float4*)&f2r[((tt) + 2) * 32 + pm4];                                        \
        }                                                                                            \
    } else {                                                                                         \
        _Pragma("unroll") for (int i = 0; i < 8; i++) {                                              \
            int v = j + i * 256;                                                                     \
            int dd = v >> 2, mc = (v & 3) * 8;                                                       \
            uint2 lo; lo.x = wreg[i].x; lo.y = wreg[i].y;                                            \
            uint2 hi; hi.x = wreg[i].z; hi.y = wreg[i].w;                                            \
            *(uint2*)&Whl[cc][dd * PLS + mc] = lo;                                                   \
            *(uint2*)&Whl[cc][dd * PLS + mc + 4] = hi;                                               \
        }                                                                                            \
        if ((tt) + 1 < NT) {                                                                         \
            _Pragma("unroll") for (int i = 0; i < 8; i++) {                                          \
                int v = j + i * 256;                                                                 \
                int dd = v >> 2, mc = (v & 3) * 8;                                                   \
                wreg[i] = *(const uint4*)&WhT[((size_t)r * D + dd) * N + ((tt) + 1) * 32 + mc];      \
            }                                                                                        \
        }                                                                                            \
    }

#define MFMASTEP(cc)                                                                                 \
    {                                                                                                \
        union UA { bf16x8_t v; uint2 u[2]; };                                                        \
        UA a[2], bb;                                                                                 \
        _Pragma("unroll") for (int nf = 0; nf < 2; nf++) {                                           \
            int arow = nf * 16 + rs;                                                                 \
            a[nf].u[0] = *(const uint2*)&Pl[cc][arow * PLS + 4 * g];                                 \
            a[nf].u[1] = *(const uint2*)&Pl[cc][arow * PLS + 16 + 4 * g];                            \
        }                                                                                            \
        _Pragma("unroll") for (int df = 0; df < 4; df++) {                                           \
            int brow = w * 64 + df * 16 + rs;                                                        \
            bb.u[0] = *(const uint2*)&Whl[cc][brow * PLS + 4 * g];                                   \
            bb.u[1] = *(const uint2*)&Whl[cc][brow * PLS + 16 + 4 * g];                              \
            acc[0][df] = __builtin_amdgcn_mfma_f32_16x16x32_bf16(a[0].v, bb.v, acc[0][df], 0, 0, 0); \
            acc[1][df] = __builtin_amdgcn_mfma_f32_16x16x32_bf16(a[1].v, bb.v, acc[1][df], 0, 0, 0); \
        }                                                                                            \
    }

    PRODUCE(0, 0, avA, fvA);
    __syncthreads();
    for (int t = 0; t < NT; t += 2) {
        if (t + 1 < NT) { PRODUCE(t + 1, 1, avB, fvB); }
        MFMASTEP(0);
        __syncthreads();
        if (t + 2 < NT) { PRODUCE(t + 2, 0, avA, fvA); }
        MFMASTEP(1);
        __syncthreads();
    }
#undef PRODUCE
#undef MFMASTEP
    // final l: reduce myl over the 8 producer threads of each row, publish, normalize, ELU, store.
    if (tid < 256) {
        float v = myl;
#pragma unroll
        for (int msk = 1; msk < 8; msk <<= 1) v += __shfl_xor(v, msk, 8);
        if ((tid & 7) == 0) sl[pn] = v;
    }
    __syncthreads();
    float inv[2][4];
#pragma unroll
    for (int nf = 0; nf < 2; nf++)
#pragma unroll
        for (int reg = 0; reg < 4; reg++) inv[nf][reg] = 1.f / sl[nf * 16 + 4 * g + reg];
#pragma unroll
    for (int nf = 0; nf < 2; nf++)
#pragma unroll
        for (int df = 0; df < 4; df++)
#pragma unroll
            for (int reg = 0; reg < 4; reg++) {
                int n = n0 + nf * 16 + 4 * g + reg;
                int d = w * 64 + df * 16 + rs;
                float v = acc[nf][df][reg] * inv[nf][reg];
                v = v > 0.f ? v : (__expf(v) - 1.f);
                stf(&xr[((size_t)r * N + n) * D + d], v);
            }
}

// ---------------- LayerNorm per (r,n) row then max over r (bf16->bf16) ----------------
__global__ __launch_bounds__(256) void k_lnmax(const bf16* __restrict__ xr, const float* __restrict__ g,
                                               const float* __restrict__ b, bf16* __restrict__ xout) {
    int n = blockIdx.x;
    int tid = threadIdx.x;
    int wave = tid >> 6, lane = tid & 63;
    __shared__ float redA[4], redB[4];
    float g0 = g[tid], g1 = g[tid + 256];
    float bb0 = b[tid], bb1 = b[tid + 256];
    float mx0 = -3e38f, mx1 = -3e38f;
    for (int r = 0; r < R; r++) {
        const bf16* row = xr + ((size_t)(r * N + n)) * D;
        float v0 = ldf(&row[tid]), v1 = ldf(&row[tid + 256]);
        float s = v0 + v1;
        float ss = fmaf(v0, v0, v1 * v1);
        s = waveReduceSum(s);
        ss = waveReduceSum(ss);
        if (lane == 0) { redA[wave] = s; redB[wave] = ss; }
        __syncthreads();
        float mu = ((redA[0] + redA[1]) + (redA[2] + redA[3])) * (1.f / D);
        float ex2 = ((redB[0] + redB[1]) + (redB[2] + redB[3])) * (1.f / D);
        float inv = 1.f / sqrtf(ex2 - mu * mu + LNEPS);
        mx0 = fmaxf(mx0, (v0 - mu) * inv * g0 + bb0);
        mx1 = fmaxf(mx1, (v1 - mu) * inv * g1 + bb1);
        __syncthreads();
    }
    stf(&xout[n * D + tid], mx0);
    stf(&xout[n * D + tid + 256], mx1);
}

// ---------------- final decoder round: max over r, f32 out ----------------
__global__ __launch_bounds__(256) void k_maxout(const bf16* __restrict__ xr, float* __restrict__ out) {
    size_t idx = (size_t)blockIdx.x * 256 + threadIdx.x;
    float m = ldf(&xr[idx]);
    m = fmaxf(m, ldf(&xr[(size_t)N * D + idx]));
    m = fmaxf(m, ldf(&xr[2 * (size_t)N * D + idx]));
    m = fmaxf(m, ldf(&xr[3 * (size_t)N * D + idx]));
    out[idx] = m;
}

// ---------------- choices head, phase 1: per-candidate dots ----------------
__global__ __launch_bounds__(256) void k_cscore(const bf16* __restrict__ xe, const int* __restrict__ cidx,
                                                const float* __restrict__ qproj, const float* __restrict__ Wout,
                                                float* __restrict__ scw, float* __restrict__ dvw) {
    int wv = threadIdx.x >> 6, lane = threadIdx.x & 63;
    int p = blockIdx.x * 4 + wv;  // 0..319 = k*64+c
    const bf16* row = xe + (size_t)cidx[p] * D;
    float s1 = 0.f, s2 = 0.f;
#pragma unroll
    for (int i = 0; i < 8; i++) {
        int d = lane + i * 64;
        float v = ldf(&row[d]);
        s1 = fmaf(v, qproj[d], s1);
        s2 = fmaf(v, Wout[d], s2);
    }
    s1 = waveReduceSum(s1);
    s2 = waveReduceSum(s2);
    if (lane == 0) { scw[p] = s1; dvw[p] = s2; }
}

// ---------------- choices head, phase 2: softmax + logits + log_softmax ----------------
__global__ __launch_bounds__(64) void k_cfinal(const float* __restrict__ scw, const float* __restrict__ dvw,
                                               const float* __restrict__ bout, float* __restrict__ out) {
    int lane = threadIdx.x;
    __shared__ float lg[5];
    for (int k = 0; k < 5; k++) {
        float v = scw[k * NC + lane];
        float m = waveReduceMax(v);
        m = __shfl(m, 0, 64);
        float e = __expf(v - m);
        float s = waveReduceSum(e);
        s = __shfl(s, 0, 64);
        float t = (e / s) * dvw[k * NC + lane];
        t = waveReduceSum(t);
        if (lane == 0) lg[k] = t + bout[0];
    }
    __syncthreads();
    if (lane == 0) {
        float m = -3e38f;
        for (int k = 0; k < 5; k++) m = fmaxf(m, lg[k]);
        float s = 0.f;
        for (int k = 0; k < 5; k++) s += __expf(lg[k] - m);
        float lse = logf(s) + m;
        for (int k = 0; k < 5; k++) out[k] = lg[k] - lse;
    }
}

extern "C" void kernel_launch(void* const* d_in, const int* in_sizes, int n_in,
                              void* d_out, int out_size, void* d_ws, size_t ws_size,
                              hipStream_t stream) {
    bool skipQ = false;
    if (n_in > 4 && in_sizes[4] != 5 * NC && in_sizes[3] == 5 * NC) skipQ = true;
    auto IN = [&](int i) -> const void* {
        int j = (skipQ && i >= 4) ? i - 1 : i;
        return d_in[j];
    };
    const float* x = (const float*)IN(0);
    const int* adj = (const int*)IN(1);
    const float* qe1 = (const float*)IN(2);
    const int* cidx = (const int*)IN(4);
    const float* Wc = (const float*)IN(5);
    const float* bc = (const float*)IN(6);
    const float* wq = (const float*)IN(7);
    const float* encW = (const float*)IN(8);
    const float* enca1 = (const float*)IN(9);
    const float* enca2 = (const float*)IN(10);
    const float* decW = (const float*)IN(11);
    const float* deca1 = (const float*)IN(12);
    const float* deca2 = (const float*)IN(13);
    const float* lng = (const float*)IN(14);
    const float* lnb = (const float*)IN(15);
    const float* Wqc = (const float*)IN(16);
    const float* bqc = (const float*)IN(17);
    const float* Wout = (const float*)IN(18);
    const float* bout = (const float*)IN(19);
    float* out = (float*)d_out;  // f32 output (proven round 6)

    // Workspace: 21,110,784 B total — round-7-proven footprint.
    char* w8 = (char*)d_ws;
    float* qemb = (float*)(w8 + 0);
    float* vvec = (float*)(w8 + 2048);
    float* qproj = (float*)(w8 + 4096);
    float* c0 = (float*)(w8 + 6144);
    float* f1 = (float*)(w8 + 8192);
    float* f2 = (float*)(w8 + 8192 + 32768);
    float* scw = (float*)(w8 + 8192 + 65536);
    float* dvw = (float*)(w8 + 8192 + 98304);
    const size_t ND = (size_t)N * D;
    bf16* xcur = (bf16*)(w8 + 139264);                       // 2 MB
    bf16* xd = (bf16*)(w8 + 139264 + ND * 2);                // 2 MB
    short* WhT = (short*)(w8 + 139264 + ND * 4);             // 8 MB
    bf16* xr = (bf16*)(w8 + 139264 + ND * 4 + R * ND * 2);   // 8 MB
    short* Wt = (short*)xr;  // per-layer bf16 weights (2 MB) alias xr; lifetimes disjoint

    k_prep<<<1, 512, 0, stream>>>(qe1, wq, Wc, bc, Wqc, bqc, qemb, vvec, qproj, c0);
    k_gate<<<N, 256, 0, stream>>>(x, vvec, qemb, c0, xcur);

    for (int L = 0; L < 4; L++) {
        const float* Wb = (L < 2) ? encW + (size_t)L * R * D * D : decW + (size_t)(L - 2) * R * D * D;
        const float* a1 = (L < 2) ? enca1 + L * R * D : deca1 + (L - 2) * R * D;
        const float* a2 = (L < 2) ? enca2 + L * R * D : deca2 + (L - 2) * R * D;
        const bf16* xin = (L == 3) ? xd : xcur;
        k_prepw<<<dim3(16, 16, R), 256, 0, stream>>>(Wb, Wt, f1, f2);
        k_gemm_mfma<<<dim3(N / 64, D / 64, R), 256, 0, stream>>>(xin, Wt, WhT, a1, a2, f1, f2);
        k_pv_nm<<<dim3(N / 32, R), 512, 0, stream>>>(adj, f1, f2, WhT, xr);
        if (L < 3)
            k_lnmax<<<N, 256, 0, stream>>>(xr, lng, lnb, (L < 2) ? xcur : xd);
        else
            k_maxout<<<N * D / 256, 256, 0, stream>>>(xr, out + 5);
    }
    k_cscore<<<80, 256, 0, stream>>>(xcur, cidx, qproj, Wout, scw, dvw);
    k_cfinal<<<1, 64, 0, stream>>>(scw, dvw, bout, out);
}